// Round 1
// baseline (954.046 us; speedup 1.0000x reference)
//
#include <hip/hip_runtime.h>
#include <math.h>

#define Bb 256
#define Nn 4096
#define Cc 256
#define Rr 32
#define Kk 128
#define Lflat (Nn * Rr)          // 131072, flattened (n,r) length per prototype
#define GCHUNKS 32
#define GCHLEN (Lflat / GCHUNKS) // 4096
#define LN2f 0.6931471805599453f

// ---- monotone float<->uint mapping for radix-style top-k threshold search ----
__device__ inline unsigned f2u(float f) {
  unsigned b = __float_as_uint(f);
  return (b & 0x80000000u) ? ~b : (b | 0x80000000u);
}
__device__ inline float u2f(unsigned u) {
  unsigned b = (u & 0x80000000u) ? (u ^ 0x80000000u) : ~u;
  return __uint_as_float(b);
}

// ---------------- top-k per row of A (exact K-th value via 32-bit binary search) ----
__global__ __launch_bounds__(256) void topk_kernel(const float* __restrict__ A,
                                                   int* __restrict__ tidx,
                                                   float* __restrict__ tval) {
  __shared__ unsigned su[Nn];
  __shared__ int s_cnt;
  __shared__ int s_eqidx[256];
  __shared__ int s_eqcnt;
  int b = blockIdx.x, t = threadIdx.x;
  const float* row = A + (size_t)b * Nn;
  for (int i = t; i < Nn; i += 256) su[i] = f2u(row[i]);
  __syncthreads();
  unsigned T = 0u;
  for (int bit = 31; bit >= 0; --bit) {
    unsigned cand = T | (1u << bit);
    int local = 0;
    for (int i = t; i < Nn; i += 256) local += (su[i] >= cand) ? 1 : 0;
#pragma unroll
    for (int off = 32; off; off >>= 1) local += __shfl_down(local, off, 64);
    __syncthreads();                 // previous iteration's read of s_cnt done
    if (t == 0) s_cnt = 0;
    __syncthreads();
    if ((t & 63) == 0) atomicAdd(&s_cnt, local);
    __syncthreads();
    if (s_cnt >= Kk) T = cand;       // same decision in every thread
  }
  __syncthreads();
  if (t == 0) { s_cnt = 0; s_eqcnt = 0; }
  __syncthreads();
  for (int i = t; i < Nn; i += 256) {
    unsigned u = su[i];
    if (u > T) {
      int p = atomicAdd(&s_cnt, 1);     // count(u>T) < K guaranteed
      tidx[b * Kk + p] = i;
      tval[b * Kk + p] = u2f(u);
    } else if (u == T) {
      int p = atomicAdd(&s_eqcnt, 1);
      if (p < 256) s_eqidx[p] = i;
    }
  }
  __syncthreads();
  int m = s_cnt;
  int eq = min(s_eqcnt, 256);
  if (t == 0) {                         // rare tie path: pick smallest indices (jax order)
    float tv = u2f(T);
    for (int s = m; s < Kk; ++s) {
      int best = 0x7fffffff, bi = 0;
      for (int j = 0; j < eq; ++j)
        if (s_eqidx[j] < best) { best = s_eqidx[j]; bi = j; }
      tidx[b * Kk + s] = best;
      tval[b * Kk + s] = tv;
      s_eqidx[bi] = 0x7fffffff;
    }
  }
}

// ---------------- score_w = A @ (softplus(W)-ln2)^T, fp32 tiled GEMM ----------------
__global__ __launch_bounds__(256) void scorew_kernel(const float* __restrict__ A,
                                                     const float* __restrict__ W,
                                                     float* __restrict__ SW) {
  __shared__ float As[32][65];
  __shared__ float Ws[32][65];
  int cb = blockIdx.x * 32, bb = blockIdx.y * 32;
  int t = threadIdx.x;
  int tx = t & 15, ty = t >> 4;
  float acc00 = 0.f, acc01 = 0.f, acc10 = 0.f, acc11 = 0.f;
  for (int k0 = 0; k0 < Nn; k0 += 64) {
    for (int e = t; e < 2048; e += 256) {
      int i = e >> 6, kk = e & 63;
      As[i][kk] = A[(size_t)(bb + i) * Nn + k0 + kk];
      float w = W[(size_t)(cb + i) * Nn + k0 + kk];
      Ws[i][kk] = fmaxf(w, 0.f) + log1pf(expf(-fabsf(w))) - LN2f;  // softplus - ln2
    }
    __syncthreads();
#pragma unroll 8
    for (int kk = 0; kk < 64; ++kk) {
      float a0 = As[ty * 2][kk], a1 = As[ty * 2 + 1][kk];
      float w0 = Ws[tx * 2][kk], w1 = Ws[tx * 2 + 1][kk];
      acc00 = fmaf(a0, w0, acc00);
      acc01 = fmaf(a0, w1, acc01);
      acc10 = fmaf(a1, w0, acc10);
      acc11 = fmaf(a1, w1, acc11);
    }
    __syncthreads();
  }
  SW[(size_t)(bb + ty * 2) * Cc + cb + tx * 2]         = acc00;
  SW[(size_t)(bb + ty * 2) * Cc + cb + tx * 2 + 1]     = acc01;
  SW[(size_t)(bb + ty * 2 + 1) * Cc + cb + tx * 2]     = acc10;
  SW[(size_t)(bb + ty * 2 + 1) * Cc + cb + tx * 2 + 1] = acc11;
}

// ---------------- G = U_flat @ U_flat^T partials (upper-triangular 32x32 tiles) -----
__global__ __launch_bounds__(256) void gram_kernel(const float* __restrict__ U,
                                                   float* __restrict__ Gpart) {
  int l = blockIdx.x;                 // 0..35 linear upper-tri tile index
  int ti = 0;
  while (l >= 8 - ti) { l -= 8 - ti; ti++; }
  int tj = ti + l;
  int t = threadIdx.x;
  int tx = t & 15, ty = t >> 4;
  __shared__ float Us[32][65];
  __shared__ float Vs[32][65];
  size_t rowi = (size_t)(ti * 32) * Lflat;
  size_t rowj = (size_t)(tj * 32) * Lflat;
  int k0base = blockIdx.y * GCHLEN;
  float acc00 = 0.f, acc01 = 0.f, acc10 = 0.f, acc11 = 0.f;
  for (int k0 = k0base; k0 < k0base + GCHLEN; k0 += 64) {
    for (int e = t; e < 2048; e += 256) {
      int i = e >> 6, kk = e & 63;
      Us[i][kk] = U[rowi + (size_t)i * Lflat + k0 + kk];
      Vs[i][kk] = U[rowj + (size_t)i * Lflat + k0 + kk];
    }
    __syncthreads();
#pragma unroll 8
    for (int kk = 0; kk < 64; ++kk) {
      float a0 = Us[ty * 2][kk], a1 = Us[ty * 2 + 1][kk];
      float w0 = Vs[tx * 2][kk], w1 = Vs[tx * 2 + 1][kk];
      acc00 = fmaf(a0, w0, acc00);
      acc01 = fmaf(a0, w1, acc01);
      acc10 = fmaf(a1, w0, acc10);
      acc11 = fmaf(a1, w1, acc11);
    }
    __syncthreads();
  }
  float* gp = Gpart + ((size_t)blockIdx.y * 36 + blockIdx.x) * 1024;
  gp[(ty * 2) * 32 + tx * 2]           = acc00;
  gp[(ty * 2) * 32 + tx * 2 + 1]       = acc01;
  gp[(ty * 2 + 1) * 32 + tx * 2]       = acc10;
  gp[(ty * 2 + 1) * 32 + tx * 2 + 1]   = acc11;
}

__global__ __launch_bounds__(256) void gram_reduce_kernel(const float* __restrict__ Gpart,
                                                          float* __restrict__ G) {
  int l = blockIdx.x;
  int ti = 0;
  while (l >= 8 - ti) { l -= 8 - ti; ti++; }
  int tj = ti + l;
  for (int e = threadIdx.x; e < 1024; e += 256) {
    float s = 0.f;
    for (int ch = 0; ch < GCHUNKS; ++ch)
      s += Gpart[((size_t)ch * 36 + blockIdx.x) * 1024 + e];
    int i = e >> 5, j = e & 31;
    int ci = ti * 32 + i, cj = tj * 32 + j;
    G[ci * Cc + cj] = s;   // symmetric fill (diagonal-tile double writes are identical)
    G[cj * Cc + ci] = s;
  }
}

// ---------------- Au[b,c,r] = sum_k v_k * U[c, idx_k, r]; and score_coact ----------
__global__ __launch_bounds__(256) void au_kernel(const float* __restrict__ U,
                                                 const int* __restrict__ tidx,
                                                 const float* __restrict__ tval,
                                                 float* __restrict__ Au,
                                                 float* __restrict__ SC) {
  int b = blockIdx.y, cq = blockIdx.x;   // cq in 0..3, 64 c's per block
  int t = threadIdx.x;
  int r = t & 31, g = t >> 5;            // g in 0..7
  __shared__ int   sidx[Kk];
  __shared__ float sval[Kk];
  if (t < Kk) { sidx[t] = tidx[b * Kk + t]; sval[t] = tval[b * Kk + t]; }
  __syncthreads();
  float acc[8];
#pragma unroll
  for (int i = 0; i < 8; ++i) acc[i] = 0.f;
  for (int k = 0; k < Kk; ++k) {
    int n = sidx[k];
    float v = sval[k];
    const float* base = U + (size_t)n * Rr + r;
#pragma unroll
    for (int cc = 0; cc < 8; ++cc) {
      int c = cq * 64 + cc * 8 + g;
      acc[cc] = fmaf(v, base[(size_t)c * Lflat], acc[cc]);
    }
  }
#pragma unroll
  for (int cc = 0; cc < 8; ++cc) {
    int c = cq * 64 + cc * 8 + g;
    Au[((size_t)b * Cc + c) * Rr + r] = acc[cc];
    float sq = acc[cc] * acc[cc];
#pragma unroll
    for (int msk = 16; msk; msk >>= 1) sq += __shfl_xor(sq, msk, 64);
    if (r == 0) SC[b * Cc + c] = sq / (float)(Kk * Rr);
  }
}

// ---------------- match scores + softmax -> beta  (mean-shift cancels in softmax) ---
__global__ __launch_bounds__(256) void softmax_kernel(const float* __restrict__ SW,
                                                      const float* __restrict__ SC,
                                                      const float* __restrict__ span_t,
                                                      const float* __restrict__ PS,
                                                      float* __restrict__ beta) {
  int b = blockIdx.x, t = threadIdx.x;
  float span_norm = fminf(fmaxf(span_t[b] * (1.f / 20.f), 0.f), 1.f);
  float psn = 1.f / (1.f + expf(-PS[t]));
  float m = SW[b * Cc + t] + SC[b * Cc + t] - 0.3f * fabsf(span_norm - psn);
  __shared__ float redM[4], redS[4];
  float mx = m;
#pragma unroll
  for (int off = 32; off; off >>= 1) mx = fmaxf(mx, __shfl_xor(mx, off, 64));
  if ((t & 63) == 0) redM[t >> 6] = mx;
  __syncthreads();
  mx = fmaxf(fmaxf(redM[0], redM[1]), fmaxf(redM[2], redM[3]));
  float e = expf(m - mx);
  float s = e;
#pragma unroll
  for (int off = 32; off; off >>= 1) s += __shfl_xor(s, off, 64);
  if ((t & 63) == 0) redS[t >> 6] = s;
  __syncthreads();
  s = redS[0] + redS[1] + redS[2] + redS[3];
  beta[b * Cc + t] = e / s;
}

// ---------------- residual: cross from beta.Au, norm_Mrecon from beta'G beta --------
__global__ __launch_bounds__(256) void final_kernel(const float* __restrict__ beta,
                                                    const float* __restrict__ G,
                                                    const float* __restrict__ Au,
                                                    const float* __restrict__ tval,
                                                    float* __restrict__ out) {
  int b = blockIdx.x, t = threadIdx.x;
  __shared__ float sb[Cc];
  __shared__ float au2[8][32];
  __shared__ float redA[4], redB[4];
  sb[t] = beta[b * Cc + t];
  __syncthreads();
  // norm_Mrecon partial: w_t = sum_c beta_c G[c,t]; pr = beta_t w_t
  float w = 0.f;
  for (int c = 0; c < Cc; ++c) w = fmaf(sb[c], G[c * Cc + t], w);
  float pr = sb[t] * w;
  // cross partials: Au2[r] = sum_c beta_c Au[b,c,r]
  int r = t & 31, g = t >> 5;
  float p = 0.f;
#pragma unroll 8
  for (int cc = 0; cc < 32; ++cc) {
    int c = cc * 8 + g;
    p = fmaf(sb[c], Au[((size_t)b * Cc + c) * Rr + r], p);
  }
  au2[g][r] = p;
  // norm_Mhat partial
  float h = (t < Kk) ? tval[b * Kk + t] * tval[b * Kk + t] : 0.f;
  float x = pr;
#pragma unroll
  for (int off = 32; off; off >>= 1) x += __shfl_xor(x, off, 64);
  if ((t & 63) == 0) redA[t >> 6] = x;
  float y = h;
#pragma unroll
  for (int off = 32; off; off >>= 1) y += __shfl_xor(y, off, 64);
  if ((t & 63) == 0) redB[t >> 6] = y;
  __syncthreads();
  float recon = (redA[0] + redA[1] + redA[2] + redA[3]) * (1.f / 4096.f);
  float mhat  = (redB[0] + redB[1] + redB[2] + redB[3]) * (1.f / 128.f);
  float cr = 0.f;
  if (t < 32) {
    float a2 = 0.f;
#pragma unroll
    for (int gg = 0; gg < 8; ++gg) a2 += au2[gg][t];
    cr = a2 * a2;
  }
#pragma unroll
  for (int off = 16; off; off >>= 1) cr += __shfl_xor(cr, off, 64);
  if (t == 0) {
    cr *= (1.f / 4096.f);
    float res = mhat - 2.f * cr + recon;
    res = fminf(fmaxf(res, 0.f), 10000.f);
    out[b] = res;
  }
}

extern "C" void kernel_launch(void* const* d_in, const int* in_sizes, int n_in,
                              void* d_out, int out_size, void* d_ws, size_t ws_size,
                              hipStream_t stream) {
  const float* A      = (const float*)d_in[0];
  const float* span_t = (const float*)d_in[1];
  const float* W      = (const float*)d_in[2];
  const float* U      = (const float*)d_in[3];
  const float* PS     = (const float*)d_in[4];
  float* out = (float*)d_out;

  char* p = (char*)d_ws;
  int*   tidx  = (int*)p;   p += (size_t)Bb * Kk * 4;
  float* tval  = (float*)p; p += (size_t)Bb * Kk * 4;
  float* SW    = (float*)p; p += (size_t)Bb * Cc * 4;
  float* SC    = (float*)p; p += (size_t)Bb * Cc * 4;
  float* beta  = (float*)p; p += (size_t)Bb * Cc * 4;
  float* G     = (float*)p; p += (size_t)Cc * Cc * 4;
  float* Au    = (float*)p; p += (size_t)Bb * Cc * Rr * 4;
  float* Gpart = (float*)p; p += (size_t)GCHUNKS * 36 * 1024 * 4;

  topk_kernel<<<dim3(Bb), dim3(256), 0, stream>>>(A, tidx, tval);
  scorew_kernel<<<dim3(8, 8), dim3(256), 0, stream>>>(A, W, SW);
  gram_kernel<<<dim3(36, GCHUNKS), dim3(256), 0, stream>>>(U, Gpart);
  gram_reduce_kernel<<<dim3(36), dim3(256), 0, stream>>>(Gpart, G);
  au_kernel<<<dim3(4, Bb), dim3(256), 0, stream>>>(U, tidx, tval, Au, SC);
  softmax_kernel<<<dim3(Bb), dim3(256), 0, stream>>>(SW, SC, span_t, PS, beta);
  final_kernel<<<dim3(Bb), dim3(256), 0, stream>>>(beta, G, Au, tval, out);
}

// Round 2
// 383.477 us; speedup vs baseline: 2.4879x; 2.4879x over previous
//
#include <hip/hip_runtime.h>
#include <math.h>

#define Bb 256
#define Nn 4096
#define Cc 256
#define Rr 32
#define Kk 128
#define Lflat (Nn * Rr)          // 131072
#define LN2f 0.6931471805599453f
#define SKC 8                    // split-K factor for scorew

typedef unsigned short u16;
typedef __attribute__((ext_vector_type(8))) short short8b;  // 8 bf16
typedef __attribute__((ext_vector_type(4))) float f32x4;

__device__ inline u16 f2bf(float x) {            // RNE float->bf16
  unsigned u = __float_as_uint(x);
  unsigned r = (u + 0x7fffu + ((u >> 16) & 1u)) >> 16;
  return (u16)r;
}

// ---- monotone float<->uint mapping for radix-style top-k threshold search ----
__device__ inline unsigned f2u(float f) {
  unsigned b = __float_as_uint(f);
  return (b & 0x80000000u) ? ~b : (b | 0x80000000u);
}
__device__ inline float u2f(unsigned u) {
  unsigned b = (u & 0x80000000u) ? (u ^ 0x80000000u) : ~u;
  return __uint_as_float(b);
}

// ---------------- top-k per row of A ----------------
__global__ __launch_bounds__(256) void topk_kernel(const float* __restrict__ A,
                                                   int* __restrict__ tidx,
                                                   float* __restrict__ tval) {
  __shared__ unsigned su[Nn];
  __shared__ int s_cnt;
  __shared__ int s_eqidx[256];
  __shared__ int s_eqcnt;
  int b = blockIdx.x, t = threadIdx.x;
  const float* row = A + (size_t)b * Nn;
  for (int i = t; i < Nn; i += 256) su[i] = f2u(row[i]);
  __syncthreads();
  unsigned T = 0u;
  for (int bit = 31; bit >= 0; --bit) {
    unsigned cand = T | (1u << bit);
    int local = 0;
    for (int i = t; i < Nn; i += 256) local += (su[i] >= cand) ? 1 : 0;
#pragma unroll
    for (int off = 32; off; off >>= 1) local += __shfl_down(local, off, 64);
    __syncthreads();
    if (t == 0) s_cnt = 0;
    __syncthreads();
    if ((t & 63) == 0) atomicAdd(&s_cnt, local);
    __syncthreads();
    if (s_cnt >= Kk) T = cand;
  }
  __syncthreads();
  if (t == 0) { s_cnt = 0; s_eqcnt = 0; }
  __syncthreads();
  for (int i = t; i < Nn; i += 256) {
    unsigned u = su[i];
    if (u > T) {
      int p = atomicAdd(&s_cnt, 1);
      tidx[b * Kk + p] = i;
      tval[b * Kk + p] = u2f(u);
    } else if (u == T) {
      int p = atomicAdd(&s_eqcnt, 1);
      if (p < 256) s_eqidx[p] = i;
    }
  }
  __syncthreads();
  int m = s_cnt;
  int eq = min(s_eqcnt, 256);
  if (t == 0) {
    float tv = u2f(T);
    for (int s = m; s < Kk; ++s) {
      int best = 0x7fffffff, bi = 0;
      for (int j = 0; j < eq; ++j)
        if (s_eqidx[j] < best) { best = s_eqidx[j]; bi = j; }
      tidx[b * Kk + s] = best;
      tval[b * Kk + s] = tv;
      s_eqidx[bi] = 0x7fffffff;
    }
  }
}

// ---------------- PW = softplus(W) - ln2 (elementwise, vectorized) ----------------
__global__ __launch_bounds__(256) void pw_kernel(const float* __restrict__ W,
                                                 float* __restrict__ PW) {
  int i = blockIdx.x * 256 + threadIdx.x;     // 1048576/4 = 262144 float4's
  float4 w = ((const float4*)W)[i];
  float4 o;
  o.x = fmaxf(w.x, 0.f) + log1pf(expf(-fabsf(w.x))) - LN2f;
  o.y = fmaxf(w.y, 0.f) + log1pf(expf(-fabsf(w.y))) - LN2f;
  o.z = fmaxf(w.z, 0.f) + log1pf(expf(-fabsf(w.z))) - LN2f;
  o.w = fmaxf(w.w, 0.f) + log1pf(expf(-fabsf(w.w))) - LN2f;
  ((float4*)PW)[i] = o;
}

// ---------------- score_w split-K fp32 GEMM: SWp[kc][b][c] ----------------
__global__ __launch_bounds__(256) void scorew_kernel(const float* __restrict__ A,
                                                     const float* __restrict__ PW,
                                                     float* __restrict__ SWp) {
  __shared__ float As[32][65];
  __shared__ float Ws[32][65];
  int cb = blockIdx.x * 32, bb = blockIdx.y * 32, kc = blockIdx.z;
  int t = threadIdx.x;
  int tx = t & 15, ty = t >> 4;
  float acc00 = 0.f, acc01 = 0.f, acc10 = 0.f, acc11 = 0.f;
  int kbeg = kc * (Nn / SKC);
  for (int k0 = kbeg; k0 < kbeg + Nn / SKC; k0 += 64) {
    for (int e = t; e < 2048; e += 256) {
      int i = e >> 6, kk = e & 63;
      As[i][kk] = A[(size_t)(bb + i) * Nn + k0 + kk];
      Ws[i][kk] = PW[(size_t)(cb + i) * Nn + k0 + kk];
    }
    __syncthreads();
#pragma unroll 8
    for (int kk = 0; kk < 64; ++kk) {
      float a0 = As[ty * 2][kk], a1 = As[ty * 2 + 1][kk];
      float w0 = Ws[tx * 2][kk], w1 = Ws[tx * 2 + 1][kk];
      acc00 = fmaf(a0, w0, acc00);
      acc01 = fmaf(a0, w1, acc01);
      acc10 = fmaf(a1, w0, acc10);
      acc11 = fmaf(a1, w1, acc11);
    }
    __syncthreads();
  }
  float* o = SWp + (size_t)kc * (Bb * Cc);
  o[(size_t)(bb + ty * 2) * Cc + cb + tx * 2]         = acc00;
  o[(size_t)(bb + ty * 2) * Cc + cb + tx * 2 + 1]     = acc01;
  o[(size_t)(bb + ty * 2 + 1) * Cc + cb + tx * 2]     = acc10;
  o[(size_t)(bb + ty * 2 + 1) * Cc + cb + tx * 2 + 1] = acc11;
}

// ---------------- Gram via bf16 MFMA: 3 triangular 128x128 tiles, split-K ----------
// tile 0:(0,0) diag, 1:(0,1), 2:(1,1) diag. bx = chunk*3 + tile.
__global__ __launch_bounds__(256) void gram_mfma_kernel(const float* __restrict__ U,
                                                        float* __restrict__ Gpart,
                                                        int kch) {
  int bx = blockIdx.x;
  int tile = bx % 3;
  int chunk = bx / 3;
  int ti = (tile == 2) ? 1 : 0;
  int tj = (tile == 0) ? 0 : 1;
  bool diag = (tile != 1);
  int t = threadIdx.x;
  int lane = t & 63, wave = t >> 6;
  int lo = lane & 15, hi = lane >> 4;
  int wr = wave >> 1, wc = wave & 1;

  __shared__ __align__(16) u16 lp[2][128 * 64];   // XOR-swizzled bf16 panels

  size_t kbase = (size_t)chunk * kch;
  f32x4 acc[4][4];
#pragma unroll
  for (int m = 0; m < 4; ++m)
#pragma unroll
    for (int n = 0; n < 4; ++n) acc[m][n] = (f32x4){0.f, 0.f, 0.f, 0.f};

  int nslots = diag ? 1024 : 2048;
  for (int k0 = 0; k0 < kch; k0 += 64) {
    // stage: slot = row(7b) x chunk-of-8-bf16(3b); swizzle chunk ^= row&7
    for (int s = t; s < nslots; s += 256) {
      int panel = s >> 10;
      int sl = s & 1023;
      int row = sl >> 3, q = sl & 7;
      int grow = (panel ? tj : ti) * 128 + row;
      const float* src = U + (size_t)grow * Lflat + kbase + k0 + q * 8;
      float4 f0 = *(const float4*)src;
      float4 f1 = *(const float4*)(src + 4);
      union { short8b v; u16 u[8]; } pk;
      pk.u[0] = f2bf(f0.x); pk.u[1] = f2bf(f0.y); pk.u[2] = f2bf(f0.z); pk.u[3] = f2bf(f0.w);
      pk.u[4] = f2bf(f1.x); pk.u[5] = f2bf(f1.y); pk.u[6] = f2bf(f1.z); pk.u[7] = f2bf(f1.w);
      *(short8b*)(&lp[panel][row * 64 + ((q ^ (row & 7)) << 3)]) = pk.v;
    }
    __syncthreads();
#pragma unroll
    for (int ks = 0; ks < 2; ++ks) {
      short8b af[4], bfv[4];
#pragma unroll
      for (int m = 0; m < 4; ++m) {
        int row = wr * 64 + m * 16 + lo;
        int q = ks * 4 + hi;
        af[m] = *(const short8b*)(&lp[0][row * 64 + ((q ^ (row & 7)) << 3)]);
      }
      const u16* pb = diag ? lp[0] : lp[1];
#pragma unroll
      for (int n = 0; n < 4; ++n) {
        int row = wc * 64 + n * 16 + lo;
        int q = ks * 4 + hi;
        bfv[n] = *(const short8b*)(&pb[row * 64 + ((q ^ (row & 7)) << 3)]);
      }
#pragma unroll
      for (int m = 0; m < 4; ++m)
#pragma unroll
        for (int n = 0; n < 4; ++n)
          acc[m][n] = __builtin_amdgcn_mfma_f32_16x16x32_bf16(af[m], bfv[n], acc[m][n], 0, 0, 0);
    }
    __syncthreads();
  }
  // epilogue: C/D layout col=lane&15, row=(lane>>4)*4+reg  [m89/m91]
  float* gp = Gpart + (size_t)bx * 16384;
#pragma unroll
  for (int m = 0; m < 4; ++m)
#pragma unroll
    for (int n = 0; n < 4; ++n)
#pragma unroll
      for (int r = 0; r < 4; ++r) {
        int row = wr * 64 + m * 16 + hi * 4 + r;
        int col = wc * 64 + n * 16 + lo;
        gp[row * 128 + col] = acc[m][n][r];
      }
}

__global__ __launch_bounds__(256) void gram_reduce_kernel(const float* __restrict__ Gpart,
                                                          float* __restrict__ G,
                                                          int nchunks) {
  int tile = blockIdx.x % 3, seg = blockIdx.x / 3;   // grid = 3*16
  int ti = (tile == 2) ? 1 : 0;
  int tj = (tile == 0) ? 0 : 1;
  int e = seg * 1024 + threadIdx.x * 4;
  float4 s = {0.f, 0.f, 0.f, 0.f};
  for (int ch = 0; ch < nchunks; ++ch) {
    float4 v = *(const float4*)(Gpart + ((size_t)(ch * 3 + tile)) * 16384 + e);
    s.x += v.x; s.y += v.y; s.z += v.z; s.w += v.w;
  }
  int row = e >> 7, col = e & 127;
  int gi = ti * 128 + row, gj = tj * 128 + col;
  G[gi * Cc + gj + 0] = s.x;
  G[gi * Cc + gj + 1] = s.y;
  G[gi * Cc + gj + 2] = s.z;
  G[gi * Cc + gj + 3] = s.w;
  if (tile == 1) {
    G[(gj + 0) * Cc + gi] = s.x;
    G[(gj + 1) * Cc + gi] = s.y;
    G[(gj + 2) * Cc + gi] = s.z;
    G[(gj + 3) * Cc + gi] = s.w;
  }
}

// ---------------- Au[b,c,r] = sum_k v_k * U[c, idx_k, r]; and score_coact ----------
__global__ __launch_bounds__(256) void au_kernel(const float* __restrict__ U,
                                                 const int* __restrict__ tidx,
                                                 const float* __restrict__ tval,
                                                 float* __restrict__ Au,
                                                 float* __restrict__ SC) {
  int b = blockIdx.y, cq = blockIdx.x;
  int t = threadIdx.x;
  int r = t & 31, g = t >> 5;
  __shared__ int   sidx[Kk];
  __shared__ float sval[Kk];
  if (t < Kk) { sidx[t] = tidx[b * Kk + t]; sval[t] = tval[b * Kk + t]; }
  __syncthreads();
  float acc[8];
#pragma unroll
  for (int i = 0; i < 8; ++i) acc[i] = 0.f;
  for (int k = 0; k < Kk; ++k) {
    int n = sidx[k];
    float v = sval[k];
    const float* base = U + (size_t)n * Rr + r;
#pragma unroll
    for (int cc = 0; cc < 8; ++cc) {
      int c = cq * 64 + cc * 8 + g;
      acc[cc] = fmaf(v, base[(size_t)c * Lflat], acc[cc]);
    }
  }
#pragma unroll
  for (int cc = 0; cc < 8; ++cc) {
    int c = cq * 64 + cc * 8 + g;
    Au[((size_t)b * Cc + c) * Rr + r] = acc[cc];
    float sq = acc[cc] * acc[cc];
#pragma unroll
    for (int msk = 16; msk; msk >>= 1) sq += __shfl_xor(sq, msk, 64);
    if (r == 0) SC[b * Cc + c] = sq / (float)(Kk * Rr);
  }
}

// ---------------- match scores (incl. SWp partial-sum) + softmax -> beta -----------
__global__ __launch_bounds__(256) void softmax_kernel(const float* __restrict__ SWp,
                                                      const float* __restrict__ SC,
                                                      const float* __restrict__ span_t,
                                                      const float* __restrict__ PS,
                                                      float* __restrict__ beta) {
  int b = blockIdx.x, t = threadIdx.x;
  float span_norm = fminf(fmaxf(span_t[b] * (1.f / 20.f), 0.f), 1.f);
  float psn = 1.f / (1.f + expf(-PS[t]));
  float m = 0.f;
#pragma unroll
  for (int kc = 0; kc < SKC; ++kc) m += SWp[(size_t)kc * (Bb * Cc) + b * Cc + t];
  m += SC[b * Cc + t] - 0.3f * fabsf(span_norm - psn);
  __shared__ float redM[4], redS[4];
  float mx = m;
#pragma unroll
  for (int off = 32; off; off >>= 1) mx = fmaxf(mx, __shfl_xor(mx, off, 64));
  if ((t & 63) == 0) redM[t >> 6] = mx;
  __syncthreads();
  mx = fmaxf(fmaxf(redM[0], redM[1]), fmaxf(redM[2], redM[3]));
  float e = expf(m - mx);
  float s = e;
#pragma unroll
  for (int off = 32; off; off >>= 1) s += __shfl_xor(s, off, 64);
  if ((t & 63) == 0) redS[t >> 6] = s;
  __syncthreads();
  s = redS[0] + redS[1] + redS[2] + redS[3];
  beta[b * Cc + t] = e / s;
}

// ---------------- residual ----------------
__global__ __launch_bounds__(256) void final_kernel(const float* __restrict__ beta,
                                                    const float* __restrict__ G,
                                                    const float* __restrict__ Au,
                                                    const float* __restrict__ tval,
                                                    float* __restrict__ out) {
  int b = blockIdx.x, t = threadIdx.x;
  __shared__ float sb[Cc];
  __shared__ float au2[8][32];
  __shared__ float redA[4], redB[4];
  sb[t] = beta[b * Cc + t];
  __syncthreads();
  float w = 0.f;
  for (int c = 0; c < Cc; ++c) w = fmaf(sb[c], G[c * Cc + t], w);
  float pr = sb[t] * w;
  int r = t & 31, g = t >> 5;
  float p = 0.f;
#pragma unroll 8
  for (int cc = 0; cc < 32; ++cc) {
    int c = cc * 8 + g;
    p = fmaf(sb[c], Au[((size_t)b * Cc + c) * Rr + r], p);
  }
  au2[g][r] = p;
  float h = (t < Kk) ? tval[b * Kk + t] * tval[b * Kk + t] : 0.f;
  float x = pr;
#pragma unroll
  for (int off = 32; off; off >>= 1) x += __shfl_xor(x, off, 64);
  if ((t & 63) == 0) redA[t >> 6] = x;
  float y = h;
#pragma unroll
  for (int off = 32; off; off >>= 1) y += __shfl_xor(y, off, 64);
  if ((t & 63) == 0) redB[t >> 6] = y;
  __syncthreads();
  float recon = (redA[0] + redA[1] + redA[2] + redA[3]) * (1.f / 4096.f);
  float mhat  = (redB[0] + redB[1] + redB[2] + redB[3]) * (1.f / 128.f);
  float cr = 0.f;
  if (t < 32) {
    float a2 = 0.f;
#pragma unroll
    for (int gg = 0; gg < 8; ++gg) a2 += au2[gg][t];
    cr = a2 * a2;
  }
#pragma unroll
  for (int off = 16; off; off >>= 1) cr += __shfl_xor(cr, off, 64);
  if (t == 0) {
    cr *= (1.f / 4096.f);
    float res = mhat - 2.f * cr + recon;
    res = fminf(fmaxf(res, 0.f), 10000.f);
    out[b] = res;
  }
}

extern "C" void kernel_launch(void* const* d_in, const int* in_sizes, int n_in,
                              void* d_out, int out_size, void* d_ws, size_t ws_size,
                              hipStream_t stream) {
  const float* A      = (const float*)d_in[0];
  const float* span_t = (const float*)d_in[1];
  const float* W      = (const float*)d_in[2];
  const float* U      = (const float*)d_in[3];
  const float* PS     = (const float*)d_in[4];
  float* out = (float*)d_out;

  char* p = (char*)d_ws;
  int*   tidx = (int*)p;   p += (size_t)Bb * Kk * 4;
  float* tval = (float*)p; p += (size_t)Bb * Kk * 4;
  float* SWp  = (float*)p; p += (size_t)SKC * Bb * Cc * 4;
  float* SC   = (float*)p; p += (size_t)Bb * Cc * 4;
  float* beta = (float*)p; p += (size_t)Bb * Cc * 4;
  float* G    = (float*)p; p += (size_t)Cc * Cc * 4;
  float* PW   = (float*)p; p += (size_t)Cc * Nn * 4;
  float* Au   = (float*)p; p += (size_t)Bb * Cc * Rr * 4;
  size_t fixed = (size_t)(p - (char*)d_ws);
  int nchunks = 64;                       // Gpart: 3*nchunks*128*128*4 bytes
  while (nchunks > 8 && fixed + (size_t)(3 * nchunks) * 16384 * 4 > ws_size) nchunks >>= 1;
  float* Gpart = (float*)p;

  topk_kernel<<<dim3(Bb), dim3(256), 0, stream>>>(A, tidx, tval);
  pw_kernel<<<dim3((Cc * Nn / 4) / 256), dim3(256), 0, stream>>>(W, PW);
  scorew_kernel<<<dim3(8, 8, SKC), dim3(256), 0, stream>>>(A, PW, SWp);
  gram_mfma_kernel<<<dim3(3 * nchunks), dim3(256), 0, stream>>>(U, Gpart, Lflat / nchunks);
  gram_reduce_kernel<<<dim3(48), dim3(256), 0, stream>>>(Gpart, G, nchunks);
  au_kernel<<<dim3(4, Bb), dim3(256), 0, stream>>>(U, tidx, tval, Au, SC);
  softmax_kernel<<<dim3(Bb), dim3(256), 0, stream>>>(SWp, SC, span_t, PS, beta);
  final_kernel<<<dim3(Bb), dim3(256), 0, stream>>>(beta, G, Au, tval, out);
}

// Round 3
// 358.632 us; speedup vs baseline: 2.6602x; 1.0693x over previous
//
#include <hip/hip_runtime.h>
#include <math.h>

#define Bb 256
#define Nn 4096
#define Cc 256
#define Rr 32
#define Kk 128
#define Lflat (Nn * Rr)          // 131072
#define LN2f 0.6931471805599453f
#define SKW 16                   // split-K factor for scorew MFMA

typedef unsigned short u16;
typedef __attribute__((ext_vector_type(8))) short short8b;  // 8 bf16
typedef __attribute__((ext_vector_type(4))) float f32x4;

__device__ inline u16 f2bf(float x) {            // RNE float->bf16
  unsigned u = __float_as_uint(x);
  unsigned r = (u + 0x7fffu + ((u >> 16) & 1u)) >> 16;
  return (u16)r;
}

// ---- monotone float<->uint mapping for radix-style top-k threshold search ----
__device__ inline unsigned f2u(float f) {
  unsigned b = __float_as_uint(f);
  return (b & 0x80000000u) ? ~b : (b | 0x80000000u);
}
__device__ inline float u2f(unsigned u) {
  unsigned b = (u & 0x80000000u) ? (u ^ 0x80000000u) : ~u;
  return __uint_as_float(b);
}

// ---------------- top-k per row of A ----------------
__global__ __launch_bounds__(256) void topk_kernel(const float* __restrict__ A,
                                                   int* __restrict__ tidx,
                                                   float* __restrict__ tval) {
  __shared__ unsigned su[Nn];
  __shared__ int s_cnt;
  __shared__ int s_eqidx[256];
  __shared__ int s_eqcnt;
  int b = blockIdx.x, t = threadIdx.x;
  const float* row = A + (size_t)b * Nn;
  for (int i = t; i < Nn; i += 256) su[i] = f2u(row[i]);
  __syncthreads();
  unsigned T = 0u;
  for (int bit = 31; bit >= 0; --bit) {
    unsigned cand = T | (1u << bit);
    int local = 0;
    for (int i = t; i < Nn; i += 256) local += (su[i] >= cand) ? 1 : 0;
#pragma unroll
    for (int off = 32; off; off >>= 1) local += __shfl_down(local, off, 64);
    __syncthreads();
    if (t == 0) s_cnt = 0;
    __syncthreads();
    if ((t & 63) == 0) atomicAdd(&s_cnt, local);
    __syncthreads();
    if (s_cnt >= Kk) T = cand;
  }
  __syncthreads();
  if (t == 0) { s_cnt = 0; s_eqcnt = 0; }
  __syncthreads();
  for (int i = t; i < Nn; i += 256) {
    unsigned u = su[i];
    if (u > T) {
      int p = atomicAdd(&s_cnt, 1);
      tidx[b * Kk + p] = i;
      tval[b * Kk + p] = u2f(u);
    } else if (u == T) {
      int p = atomicAdd(&s_eqcnt, 1);
      if (p < 256) s_eqidx[p] = i;
    }
  }
  __syncthreads();
  int m = s_cnt;
  int eq = min(s_eqcnt, 256);
  if (t == 0) {
    float tv = u2f(T);
    for (int s = m; s < Kk; ++s) {
      int best = 0x7fffffff, bi = 0;
      for (int j = 0; j < eq; ++j)
        if (s_eqidx[j] < best) { best = s_eqidx[j]; bi = j; }
      tidx[b * Kk + s] = best;
      tval[b * Kk + s] = tv;
      s_eqidx[bi] = 0x7fffffff;
    }
  }
}

// ---------------- densify S: S[b][n] = v at topk indices, else 0 (bf16) -----------
__global__ __launch_bounds__(256) void scatter_kernel(const int* __restrict__ tidx,
                                                      const float* __restrict__ tval,
                                                      u16* __restrict__ S) {
  int b = blockIdx.x, t = threadIdx.x;
  short8b z = {0, 0, 0, 0, 0, 0, 0, 0};
  u16* row = S + (size_t)b * Nn;
  *(short8b*)(row + t * 16) = z;
  *(short8b*)(row + t * 16 + 8) = z;
  __syncthreads();
  if (t < Kk) row[tidx[b * Kk + t]] = f2bf(tval[b * Kk + t]);
}

// ---------------- score_w via bf16 MFMA, softplus fused in staging -----------------
// grid (4 ctile, 4 mtile, SKW). out partial SWp[ks][64b][64c].
__global__ __launch_bounds__(256) void scorew_mfma_kernel(const float* __restrict__ Ag,
                                                          const float* __restrict__ W,
                                                          float* __restrict__ SWp) {
  int ct = blockIdx.x, mt = blockIdx.y, ks = blockIdx.z;
  int t = threadIdx.x;
  int lane = t & 63, wave = t >> 6;
  int lo = lane & 15, hi = lane >> 4;
  int wr = wave >> 1, wc = wave & 1;
  __shared__ __align__(16) u16 As[64 * 64];
  __shared__ __align__(16) u16 Ws[64 * 64];
  f32x4 acc[2][2];
#pragma unroll
  for (int m = 0; m < 2; ++m)
#pragma unroll
    for (int n = 0; n < 2; ++n) acc[m][n] = (f32x4){0.f, 0.f, 0.f, 0.f};
  int kbase = ks * (Nn / SKW);
  for (int k0 = 0; k0 < Nn / SKW; k0 += 64) {
    for (int s = t; s < 1024; s += 256) {
      int panel = s >> 9;
      int sl = s & 511;
      int row = sl >> 3, q = sl & 7;
      union { short8b v; u16 u[8]; } pk;
      if (panel == 0) {
        const float* src = Ag + (size_t)(mt * 64 + row) * Nn + kbase + k0 + q * 8;
        float4 f0 = *(const float4*)src, f1 = *(const float4*)(src + 4);
        pk.u[0] = f2bf(f0.x); pk.u[1] = f2bf(f0.y); pk.u[2] = f2bf(f0.z); pk.u[3] = f2bf(f0.w);
        pk.u[4] = f2bf(f1.x); pk.u[5] = f2bf(f1.y); pk.u[6] = f2bf(f1.z); pk.u[7] = f2bf(f1.w);
        *(short8b*)(&As[row * 64 + ((q ^ (row & 7)) << 3)]) = pk.v;
      } else {
        const float* src = W + (size_t)(ct * 64 + row) * Nn + kbase + k0 + q * 8;
        float4 f0 = *(const float4*)src, f1 = *(const float4*)(src + 4);
        float w[8] = {f0.x, f0.y, f0.z, f0.w, f1.x, f1.y, f1.z, f1.w};
#pragma unroll
        for (int j = 0; j < 8; ++j)
          pk.u[j] = f2bf(fmaxf(w[j], 0.f) + log1pf(expf(-fabsf(w[j]))) - LN2f);
        *(short8b*)(&Ws[row * 64 + ((q ^ (row & 7)) << 3)]) = pk.v;
      }
    }
    __syncthreads();
#pragma unroll
    for (int kf = 0; kf < 2; ++kf) {
      int q = kf * 4 + hi;
      short8b af[2], bf[2];
#pragma unroll
      for (int m = 0; m < 2; ++m) {
        int row = wr * 32 + m * 16 + lo;
        af[m] = *(const short8b*)(&As[row * 64 + ((q ^ (row & 7)) << 3)]);
      }
#pragma unroll
      for (int n = 0; n < 2; ++n) {
        int row = wc * 32 + n * 16 + lo;
        bf[n] = *(const short8b*)(&Ws[row * 64 + ((q ^ (row & 7)) << 3)]);
      }
#pragma unroll
      for (int m = 0; m < 2; ++m)
#pragma unroll
        for (int n = 0; n < 2; ++n)
          acc[m][n] = __builtin_amdgcn_mfma_f32_16x16x32_bf16(af[m], bf[n], acc[m][n], 0, 0, 0);
    }
    __syncthreads();
  }
  float* o = SWp + (size_t)ks * (Bb * Cc);
#pragma unroll
  for (int m = 0; m < 2; ++m)
#pragma unroll
    for (int n = 0; n < 2; ++n)
#pragma unroll
      for (int r = 0; r < 4; ++r) {
        int b = mt * 64 + wr * 32 + m * 16 + hi * 4 + r;
        int c = ct * 64 + wc * 32 + n * 16 + lo;
        o[(size_t)b * Cc + c] = acc[m][n][r];
      }
}

// ---------------- Gram via bf16 MFMA: 3 triangular 128x128 tiles, split-K ----------
__global__ __launch_bounds__(256) void gram_mfma_kernel(const float* __restrict__ U,
                                                        float* __restrict__ Gpart,
                                                        int kch) {
  int bx = blockIdx.x;
  int tile = bx % 3;
  int chunk = bx / 3;
  int ti = (tile == 2) ? 1 : 0;
  int tj = (tile == 0) ? 0 : 1;
  bool diag = (tile != 1);
  int t = threadIdx.x;
  int lane = t & 63, wave = t >> 6;
  int lo = lane & 15, hi = lane >> 4;
  int wr = wave >> 1, wc = wave & 1;

  __shared__ __align__(16) u16 lp[2][128 * 64];

  size_t kbase = (size_t)chunk * kch;
  f32x4 acc[4][4];
#pragma unroll
  for (int m = 0; m < 4; ++m)
#pragma unroll
    for (int n = 0; n < 4; ++n) acc[m][n] = (f32x4){0.f, 0.f, 0.f, 0.f};

  int nslots = diag ? 1024 : 2048;
  for (int k0 = 0; k0 < kch; k0 += 64) {
    for (int s = t; s < nslots; s += 256) {
      int panel = s >> 10;
      int sl = s & 1023;
      int row = sl >> 3, q = sl & 7;
      int grow = (panel ? tj : ti) * 128 + row;
      const float* src = U + (size_t)grow * Lflat + kbase + k0 + q * 8;
      float4 f0 = *(const float4*)src;
      float4 f1 = *(const float4*)(src + 4);
      union { short8b v; u16 u[8]; } pk;
      pk.u[0] = f2bf(f0.x); pk.u[1] = f2bf(f0.y); pk.u[2] = f2bf(f0.z); pk.u[3] = f2bf(f0.w);
      pk.u[4] = f2bf(f1.x); pk.u[5] = f2bf(f1.y); pk.u[6] = f2bf(f1.z); pk.u[7] = f2bf(f1.w);
      *(short8b*)(&lp[panel][row * 64 + ((q ^ (row & 7)) << 3)]) = pk.v;
    }
    __syncthreads();
#pragma unroll
    for (int ks = 0; ks < 2; ++ks) {
      short8b af[4], bfv[4];
#pragma unroll
      for (int m = 0; m < 4; ++m) {
        int row = wr * 64 + m * 16 + lo;
        int q = ks * 4 + hi;
        af[m] = *(const short8b*)(&lp[0][row * 64 + ((q ^ (row & 7)) << 3)]);
      }
      const u16* pb = diag ? lp[0] : lp[1];
#pragma unroll
      for (int n = 0; n < 4; ++n) {
        int row = wc * 64 + n * 16 + lo;
        int q = ks * 4 + hi;
        bfv[n] = *(const short8b*)(&pb[row * 64 + ((q ^ (row & 7)) << 3)]);
      }
#pragma unroll
      for (int m = 0; m < 4; ++m)
#pragma unroll
        for (int n = 0; n < 4; ++n)
          acc[m][n] = __builtin_amdgcn_mfma_f32_16x16x32_bf16(af[m], bfv[n], acc[m][n], 0, 0, 0);
    }
    __syncthreads();
  }
  float* gp = Gpart + (size_t)bx * 16384;
#pragma unroll
  for (int m = 0; m < 4; ++m)
#pragma unroll
    for (int n = 0; n < 4; ++n)
#pragma unroll
      for (int r = 0; r < 4; ++r) {
        int row = wr * 64 + m * 16 + hi * 4 + r;
        int col = wc * 64 + n * 16 + lo;
        gp[row * 128 + col] = acc[m][n][r];
      }
}

__global__ __launch_bounds__(256) void gram_reduce_kernel(const float* __restrict__ Gpart,
                                                          float* __restrict__ G,
                                                          int nchunks) {
  int tile = blockIdx.x % 3, seg = blockIdx.x / 3;
  int ti = (tile == 2) ? 1 : 0;
  int tj = (tile == 0) ? 0 : 1;
  int e = seg * 1024 + threadIdx.x * 4;
  float4 s = {0.f, 0.f, 0.f, 0.f};
  for (int ch = 0; ch < nchunks; ++ch) {
    float4 v = *(const float4*)(Gpart + ((size_t)(ch * 3 + tile)) * 16384 + e);
    s.x += v.x; s.y += v.y; s.z += v.z; s.w += v.w;
  }
  int row = e >> 7, col = e & 127;
  int gi = ti * 128 + row, gj = tj * 128 + col;
  G[gi * Cc + gj + 0] = s.x;
  G[gi * Cc + gj + 1] = s.y;
  G[gi * Cc + gj + 2] = s.z;
  G[gi * Cc + gj + 3] = s.w;
  if (tile == 1) {
    G[(gj + 0) * Cc + gi] = s.x;
    G[(gj + 1) * Cc + gi] = s.y;
    G[(gj + 2) * Cc + gi] = s.z;
    G[(gj + 3) * Cc + gi] = s.w;
  }
}

// ---------------- Au via dense bf16 MFMA: Au[:, c, :] = S @ U[c] -------------------
// grid (c=256, mb=2). block: 128 b-rows x 32 r cols, K = 4096.
__global__ __launch_bounds__(256) void au_mfma_kernel(const float* __restrict__ U,
                                                      const u16* __restrict__ S,
                                                      float* __restrict__ Au,
                                                      float* __restrict__ SC) {
  int c = blockIdx.x, mb = blockIdx.y;
  int t = threadIdx.x;
  int lane = t & 63, wave = t >> 6;
  int lo = lane & 15, hi = lane >> 4;
  __shared__ __align__(16) u16 Ss[128 * 64];   // [row][k], swizzled
  __shared__ __align__(16) u16 Us[32 * 64];    // [r][k], swizzled
  f32x4 acc[2][2];
#pragma unroll
  for (int m = 0; m < 2; ++m)
#pragma unroll
    for (int n = 0; n < 2; ++n) acc[m][n] = (f32x4){0.f, 0.f, 0.f, 0.f};

  const float* Uc = U + (size_t)c * Lflat;
  for (int k0 = 0; k0 < Nn; k0 += 64) {
    // stage S rows (already bf16): 128 rows x 8 chunks
    for (int s = t; s < 1024; s += 256) {
      int row = s >> 3, q = s & 7;
      short8b v = *(const short8b*)(S + (size_t)(mb * 128 + row) * Nn + k0 + q * 8);
      *(short8b*)(&Ss[row * 64 + ((q ^ (row & 7)) << 3)]) = v;
    }
    // stage U[c, k0:k0+64, 0:32] transposed -> Us[r][k]
    for (int s = t; s < 512; s += 256) {
      int kk = s >> 3, rq = s & 7;
      float4 f = *(const float4*)(Uc + (size_t)(k0 + kk) * Rr + rq * 4);
      float fv[4] = {f.x, f.y, f.z, f.w};
#pragma unroll
      for (int j = 0; j < 4; ++j) {
        int r = rq * 4 + j;
        Us[r * 64 + (((kk >> 3) ^ (r & 7)) << 3) + (kk & 7)] = f2bf(fv[j]);
      }
    }
    __syncthreads();
#pragma unroll
    for (int kf = 0; kf < 2; ++kf) {
      int q = kf * 4 + hi;
      short8b af[2], bf[2];
#pragma unroll
      for (int m = 0; m < 2; ++m) {
        int row = wave * 32 + m * 16 + lo;
        af[m] = *(const short8b*)(&Ss[row * 64 + ((q ^ (row & 7)) << 3)]);
      }
#pragma unroll
      for (int n = 0; n < 2; ++n) {
        int row = n * 16 + lo;
        bf[n] = *(const short8b*)(&Us[row * 64 + ((q ^ (row & 7)) << 3)]);
      }
#pragma unroll
      for (int m = 0; m < 2; ++m)
#pragma unroll
        for (int n = 0; n < 2; ++n)
          acc[m][n] = __builtin_amdgcn_mfma_f32_16x16x32_bf16(af[m], bf[n], acc[m][n], 0, 0, 0);
    }
    __syncthreads();
  }
  // epilogue: write Au[b][c][r] and SC[b][c]
#pragma unroll
  for (int m = 0; m < 2; ++m) {
#pragma unroll
    for (int r = 0; r < 4; ++r) {
      int b = mb * 128 + wave * 32 + m * 16 + hi * 4 + r;
#pragma unroll
      for (int n = 0; n < 2; ++n) {
        int rr = n * 16 + lo;
        Au[((size_t)b * Cc + c) * Rr + rr] = acc[m][n][r];
      }
      float sq = acc[m][0][r] * acc[m][0][r] + acc[m][1][r] * acc[m][1][r];
      sq += __shfl_xor(sq, 1, 64);
      sq += __shfl_xor(sq, 2, 64);
      sq += __shfl_xor(sq, 4, 64);
      sq += __shfl_xor(sq, 8, 64);
      if (lo == 0) SC[(size_t)b * Cc + c] = sq * (1.f / (Kk * Rr));
    }
  }
}

// ---------------- match scores + softmax -> beta ----------------
__global__ __launch_bounds__(256) void softmax_kernel(const float* __restrict__ SWp,
                                                      const float* __restrict__ SC,
                                                      const float* __restrict__ span_t,
                                                      const float* __restrict__ PS,
                                                      float* __restrict__ beta) {
  int b = blockIdx.x, t = threadIdx.x;
  float span_norm = fminf(fmaxf(span_t[b] * (1.f / 20.f), 0.f), 1.f);
  float psn = 1.f / (1.f + expf(-PS[t]));
  float m = 0.f;
#pragma unroll
  for (int kc = 0; kc < SKW; ++kc) m += SWp[(size_t)kc * (Bb * Cc) + b * Cc + t];
  m += SC[b * Cc + t] - 0.3f * fabsf(span_norm - psn);
  __shared__ float redM[4], redS[4];
  float mx = m;
#pragma unroll
  for (int off = 32; off; off >>= 1) mx = fmaxf(mx, __shfl_xor(mx, off, 64));
  if ((t & 63) == 0) redM[t >> 6] = mx;
  __syncthreads();
  mx = fmaxf(fmaxf(redM[0], redM[1]), fmaxf(redM[2], redM[3]));
  float e = expf(m - mx);
  float s = e;
#pragma unroll
  for (int off = 32; off; off >>= 1) s += __shfl_xor(s, off, 64);
  if ((t & 63) == 0) redS[t >> 6] = s;
  __syncthreads();
  s = redS[0] + redS[1] + redS[2] + redS[3];
  beta[b * Cc + t] = e / s;
}

// ---------------- residual ----------------
__global__ __launch_bounds__(256) void final_kernel(const float* __restrict__ beta,
                                                    const float* __restrict__ G,
                                                    const float* __restrict__ Au,
                                                    const float* __restrict__ tval,
                                                    float* __restrict__ out) {
  int b = blockIdx.x, t = threadIdx.x;
  __shared__ float sb[Cc];
  __shared__ float au2[8][32];
  __shared__ float redA[4], redB[4];
  sb[t] = beta[b * Cc + t];
  __syncthreads();
  float w = 0.f;
  for (int c = 0; c < Cc; ++c) w = fmaf(sb[c], G[c * Cc + t], w);
  float pr = sb[t] * w;
  int r = t & 31, g = t >> 5;
  float p = 0.f;
#pragma unroll 8
  for (int cc = 0; cc < 32; ++cc) {
    int c = cc * 8 + g;
    p = fmaf(sb[c], Au[((size_t)b * Cc + c) * Rr + r], p);
  }
  au2[g][r] = p;
  float h = (t < Kk) ? tval[b * Kk + t] * tval[b * Kk + t] : 0.f;
  float x = pr;
#pragma unroll
  for (int off = 32; off; off >>= 1) x += __shfl_xor(x, off, 64);
  if ((t & 63) == 0) redA[t >> 6] = x;
  float y = h;
#pragma unroll
  for (int off = 32; off; off >>= 1) y += __shfl_xor(y, off, 64);
  if ((t & 63) == 0) redB[t >> 6] = y;
  __syncthreads();
  float recon = (redA[0] + redA[1] + redA[2] + redA[3]) * (1.f / 4096.f);
  float mhat  = (redB[0] + redB[1] + redB[2] + redB[3]) * (1.f / 128.f);
  float cr = 0.f;
  if (t < 32) {
    float a2 = 0.f;
#pragma unroll
    for (int gg = 0; gg < 8; ++gg) a2 += au2[gg][t];
    cr = a2 * a2;
  }
#pragma unroll
  for (int off = 16; off; off >>= 1) cr += __shfl_xor(cr, off, 64);
  if (t == 0) {
    cr *= (1.f / 4096.f);
    float res = mhat - 2.f * cr + recon;
    res = fminf(fmaxf(res, 0.f), 10000.f);
    out[b] = res;
  }
}

extern "C" void kernel_launch(void* const* d_in, const int* in_sizes, int n_in,
                              void* d_out, int out_size, void* d_ws, size_t ws_size,
                              hipStream_t stream) {
  const float* A      = (const float*)d_in[0];
  const float* span_t = (const float*)d_in[1];
  const float* W      = (const float*)d_in[2];
  const float* U      = (const float*)d_in[3];
  const float* PS     = (const float*)d_in[4];
  float* out = (float*)d_out;

  char* p = (char*)d_ws;
  int*   tidx = (int*)p;   p += (size_t)Bb * Kk * 4;
  float* tval = (float*)p; p += (size_t)Bb * Kk * 4;
  float* SWp  = (float*)p; p += (size_t)SKW * Bb * Cc * 4;
  float* SC   = (float*)p; p += (size_t)Bb * Cc * 4;
  float* beta = (float*)p; p += (size_t)Bb * Cc * 4;
  float* G    = (float*)p; p += (size_t)Cc * Cc * 4;
  u16*   S    = (u16*)p;   p += (size_t)Bb * Nn * 2;
  float* Au   = (float*)p; p += (size_t)Bb * Cc * Rr * 4;
  size_t fixed = (size_t)(p - (char*)d_ws);
  int nchunks = 64;
  while (nchunks > 8 && fixed + (size_t)(3 * nchunks) * 16384 * 4 > ws_size) nchunks >>= 1;
  float* Gpart = (float*)p;

  topk_kernel<<<dim3(Bb), dim3(256), 0, stream>>>(A, tidx, tval);
  scatter_kernel<<<dim3(Bb), dim3(256), 0, stream>>>(tidx, tval, S);
  scorew_mfma_kernel<<<dim3(4, 4, SKW), dim3(256), 0, stream>>>(A, W, SWp);
  gram_mfma_kernel<<<dim3(3 * nchunks), dim3(256), 0, stream>>>(U, Gpart, Lflat / nchunks);
  gram_reduce_kernel<<<dim3(48), dim3(256), 0, stream>>>(Gpart, G, nchunks);
  au_mfma_kernel<<<dim3(Cc, 2), dim3(256), 0, stream>>>(U, S, Au, SC);
  softmax_kernel<<<dim3(Bb), dim3(256), 0, stream>>>(SWp, SC, span_t, PS, beta);
  final_kernel<<<dim3(Bb), dim3(256), 0, stream>>>(beta, G, Au, tval, out);
}

// Round 4
// 211.695 us; speedup vs baseline: 4.5067x; 1.6941x over previous
//
#include <hip/hip_runtime.h>
#include <math.h>

#define Bb 256
#define Nn 4096
#define Cc 256
#define Rr 32
#define Kk 128
#define Lflat (Nn * Rr)          // 131072
#define LN2f 0.6931471805599453f
#define SKW 16                   // split-K factor for scorew MFMA

typedef unsigned short u16;
typedef __attribute__((ext_vector_type(8))) short short8b;  // 8 bf16
typedef __attribute__((ext_vector_type(4))) short short4b;  // 4 bf16
typedef __attribute__((ext_vector_type(4))) float f32x4;

typedef __attribute__((address_space(1))) const void* gas_t;
typedef __attribute__((address_space(3))) void* las_t;
__device__ __forceinline__ void gll16(const void* g, void* l) {
  __builtin_amdgcn_global_load_lds((gas_t)g, (las_t)l, 16, 0, 0);
}

__device__ inline u16 f2bf(float x) {            // RNE float->bf16
  unsigned u = __float_as_uint(x);
  unsigned r = (u + 0x7fffu + ((u >> 16) & 1u)) >> 16;
  return (u16)r;
}

// ---- monotone float<->uint mapping for radix-style top-k threshold search ----
__device__ inline unsigned f2u(float f) {
  unsigned b = __float_as_uint(f);
  return (b & 0x80000000u) ? ~b : (b | 0x80000000u);
}
__device__ inline float u2f(unsigned u) {
  unsigned b = (u & 0x80000000u) ? (u ^ 0x80000000u) : ~u;
  return __uint_as_float(b);
}

// ---------------- top-k per row of A ----------------
__global__ __launch_bounds__(256) void topk_kernel(const float* __restrict__ A,
                                                   int* __restrict__ tidx,
                                                   float* __restrict__ tval) {
  __shared__ unsigned su[Nn];
  __shared__ int s_cnt;
  __shared__ int s_eqidx[256];
  __shared__ int s_eqcnt;
  int b = blockIdx.x, t = threadIdx.x;
  const float* row = A + (size_t)b * Nn;
  for (int i = t; i < Nn; i += 256) su[i] = f2u(row[i]);
  __syncthreads();
  unsigned T = 0u;
  for (int bit = 31; bit >= 0; --bit) {
    unsigned cand = T | (1u << bit);
    int local = 0;
    for (int i = t; i < Nn; i += 256) local += (su[i] >= cand) ? 1 : 0;
#pragma unroll
    for (int off = 32; off; off >>= 1) local += __shfl_down(local, off, 64);
    __syncthreads();
    if (t == 0) s_cnt = 0;
    __syncthreads();
    if ((t & 63) == 0) atomicAdd(&s_cnt, local);
    __syncthreads();
    if (s_cnt >= Kk) T = cand;
  }
  __syncthreads();
  if (t == 0) { s_cnt = 0; s_eqcnt = 0; }
  __syncthreads();
  for (int i = t; i < Nn; i += 256) {
    unsigned u = su[i];
    if (u > T) {
      int p = atomicAdd(&s_cnt, 1);
      tidx[b * Kk + p] = i;
      tval[b * Kk + p] = u2f(u);
    } else if (u == T) {
      int p = atomicAdd(&s_eqcnt, 1);
      if (p < 256) s_eqidx[p] = i;
    }
  }
  __syncthreads();
  int m = s_cnt;
  int eq = min(s_eqcnt, 256);
  if (t == 0) {
    float tv = u2f(T);
    for (int s = m; s < Kk; ++s) {
      int best = 0x7fffffff, bi = 0;
      for (int j = 0; j < eq; ++j)
        if (s_eqidx[j] < best) { best = s_eqidx[j]; bi = j; }
      tidx[b * Kk + s] = best;
      tval[b * Kk + s] = tv;
      s_eqidx[bi] = 0x7fffffff;
    }
  }
}

// ---------------- densify S (bf16, linear layout) ----------------
__global__ __launch_bounds__(256) void scatter_kernel(const int* __restrict__ tidx,
                                                      const float* __restrict__ tval,
                                                      u16* __restrict__ S) {
  int b = blockIdx.x, t = threadIdx.x;
  short8b z = {0, 0, 0, 0, 0, 0, 0, 0};
  u16* row = S + (size_t)b * Nn;
  *(short8b*)(row + t * 16) = z;
  *(short8b*)(row + t * 16 + 8) = z;
  __syncthreads();
  if (t < Kk) row[tidx[b * Kk + t]] = f2bf(tval[b * Kk + t]);
}

// ---------------- u2t: U[c][n][r] fp32 -> UT[c][r][n] bf16 ----------------
__global__ __launch_bounds__(256) void u2t_kernel(const float* __restrict__ U,
                                                  u16* __restrict__ UT) {
  int c = blockIdx.x, nb = blockIdx.y, t = threadIdx.x;
  __shared__ u16 B16[64 * 32];
  const float* Uc = U + (size_t)c * Lflat;
  u16* UTc = UT + (size_t)c * Lflat;
  for (int it = 0; it < 8; ++it) {
    int n0 = nb * 512 + it * 64;
    __syncthreads();
    for (int u = t; u < 512; u += 256) {
      int n = u >> 3, rq = u & 7;
      float4 f = *(const float4*)(Uc + (size_t)(n0 + n) * Rr + rq * 4);
      union { short4b v; u16 s[4]; } pk;
      pk.s[0] = f2bf(f.x); pk.s[1] = f2bf(f.y); pk.s[2] = f2bf(f.z); pk.s[3] = f2bf(f.w);
      *(short4b*)(&B16[n * 32 + rq * 4]) = pk.v;
    }
    __syncthreads();
    {
      int r = t >> 3, q = t & 7;
      union { short8b v; u16 s[8]; } pk;
#pragma unroll
      for (int i = 0; i < 8; ++i) pk.s[i] = B16[(q * 8 + i) * 32 + r];
      *(short8b*)(UTc + (size_t)r * Nn + n0 + q * 8) = pk.v;
    }
  }
}

// ---------------- score_w via bf16 MFMA, softplus fused in staging -----------------
__global__ __launch_bounds__(256) void scorew_mfma_kernel(const float* __restrict__ Ag,
                                                          const float* __restrict__ W,
                                                          float* __restrict__ SWp) {
  int ct = blockIdx.x, mt = blockIdx.y, ks = blockIdx.z;
  int t = threadIdx.x;
  int lane = t & 63, wave = t >> 6;
  int lo = lane & 15, hi = lane >> 4;
  int wr = wave >> 1, wc = wave & 1;
  __shared__ __align__(16) u16 As[64 * 64];
  __shared__ __align__(16) u16 Ws[64 * 64];
  f32x4 acc[2][2];
#pragma unroll
  for (int m = 0; m < 2; ++m)
#pragma unroll
    for (int n = 0; n < 2; ++n) acc[m][n] = (f32x4){0.f, 0.f, 0.f, 0.f};
  int kbase = ks * (Nn / SKW);
  for (int k0 = 0; k0 < Nn / SKW; k0 += 64) {
    for (int s = t; s < 1024; s += 256) {
      int panel = s >> 9;
      int sl = s & 511;
      int row = sl >> 3, q = sl & 7;
      union { short8b v; u16 u[8]; } pk;
      if (panel == 0) {
        const float* src = Ag + (size_t)(mt * 64 + row) * Nn + kbase + k0 + q * 8;
        float4 f0 = *(const float4*)src, f1 = *(const float4*)(src + 4);
        pk.u[0] = f2bf(f0.x); pk.u[1] = f2bf(f0.y); pk.u[2] = f2bf(f0.z); pk.u[3] = f2bf(f0.w);
        pk.u[4] = f2bf(f1.x); pk.u[5] = f2bf(f1.y); pk.u[6] = f2bf(f1.z); pk.u[7] = f2bf(f1.w);
        *(short8b*)(&As[row * 64 + ((q ^ (row & 7)) << 3)]) = pk.v;
      } else {
        const float* src = W + (size_t)(ct * 64 + row) * Nn + kbase + k0 + q * 8;
        float4 f0 = *(const float4*)src, f1 = *(const float4*)(src + 4);
        float w[8] = {f0.x, f0.y, f0.z, f0.w, f1.x, f1.y, f1.z, f1.w};
#pragma unroll
        for (int j = 0; j < 8; ++j)
          pk.u[j] = f2bf(fmaxf(w[j], 0.f) + log1pf(expf(-fabsf(w[j]))) - LN2f);
        *(short8b*)(&Ws[row * 64 + ((q ^ (row & 7)) << 3)]) = pk.v;
      }
    }
    __syncthreads();
#pragma unroll
    for (int kf = 0; kf < 2; ++kf) {
      int q = kf * 4 + hi;
      short8b af[2], bf[2];
#pragma unroll
      for (int m = 0; m < 2; ++m) {
        int row = wr * 32 + m * 16 + lo;
        af[m] = *(const short8b*)(&As[row * 64 + ((q ^ (row & 7)) << 3)]);
      }
#pragma unroll
      for (int n = 0; n < 2; ++n) {
        int row = wc * 32 + n * 16 + lo;
        bf[n] = *(const short8b*)(&Ws[row * 64 + ((q ^ (row & 7)) << 3)]);
      }
#pragma unroll
      for (int m = 0; m < 2; ++m)
#pragma unroll
        for (int n = 0; n < 2; ++n)
          acc[m][n] = __builtin_amdgcn_mfma_f32_16x16x32_bf16(af[m], bf[n], acc[m][n], 0, 0, 0);
    }
    __syncthreads();
  }
  float* o = SWp + (size_t)ks * (Bb * Cc);
#pragma unroll
  for (int m = 0; m < 2; ++m)
#pragma unroll
    for (int n = 0; n < 2; ++n)
#pragma unroll
      for (int r = 0; r < 4; ++r) {
        int b = mt * 64 + wr * 32 + m * 16 + hi * 4 + r;
        int c = ct * 64 + wc * 32 + n * 16 + lo;
        o[(size_t)b * Cc + c] = acc[m][n][r];
      }
}

// ---------------- Gram from bf16 UT via global_load_lds ----------------
__global__ __launch_bounds__(256) void gram_bf16_kernel(const u16* __restrict__ UT,
                                                        float* __restrict__ Gpart,
                                                        int kch) {
  int bx = blockIdx.x;
  int tile = bx % 3, chunk = bx / 3;
  int ti = (tile == 2) ? 1 : 0;
  int tj = (tile == 0) ? 0 : 1;
  bool diag = (tile != 1);
  int t = threadIdx.x, lane = t & 63, wave = t >> 6;
  int lo = lane & 15, hi = lane >> 4;
  int wr = wave >> 1, wc = wave & 1;
  __shared__ __align__(16) u16 lp[2][128 * 64];
  f32x4 acc[4][4];
#pragma unroll
  for (int m = 0; m < 4; ++m)
#pragma unroll
    for (int n = 0; n < 4; ++n) acc[m][n] = (f32x4){0.f, 0.f, 0.f, 0.f};
  int lrow = lane >> 3;
  int lchunk8 = ((lane & 7) ^ lrow) * 8;   // source-side swizzle (rule #21)
  size_t kbase = (size_t)chunk * kch;
  for (int k0 = 0; k0 < kch; k0 += 64) {
    size_t kg = kbase + k0;
#pragma unroll
    for (int q = 0; q < 4; ++q) {
      int row = wave * 32 + q * 8;
      gll16(UT + (size_t)(ti * 128 + row + lrow) * Lflat + kg + lchunk8, &lp[0][row * 64]);
    }
    if (!diag) {
#pragma unroll
      for (int q = 0; q < 4; ++q) {
        int row = wave * 32 + q * 8;
        gll16(UT + (size_t)(tj * 128 + row + lrow) * Lflat + kg + lchunk8, &lp[1][row * 64]);
      }
    }
    __syncthreads();
#pragma unroll
    for (int ks = 0; ks < 2; ++ks) {
      short8b af[4], bfv[4];
#pragma unroll
      for (int m = 0; m < 4; ++m) {
        int row = wr * 64 + m * 16 + lo;
        af[m] = *(const short8b*)(&lp[0][row * 64 + (((ks * 4 + hi) ^ (row & 7)) << 3)]);
      }
      const u16* pb = diag ? lp[0] : lp[1];
#pragma unroll
      for (int n = 0; n < 4; ++n) {
        int row = wc * 64 + n * 16 + lo;
        bfv[n] = *(const short8b*)(&pb[row * 64 + (((ks * 4 + hi) ^ (row & 7)) << 3)]);
      }
#pragma unroll
      for (int m = 0; m < 4; ++m)
#pragma unroll
        for (int n = 0; n < 4; ++n)
          acc[m][n] = __builtin_amdgcn_mfma_f32_16x16x32_bf16(af[m], bfv[n], acc[m][n], 0, 0, 0);
    }
    __syncthreads();
  }
  float* gp = Gpart + (size_t)bx * 16384;
#pragma unroll
  for (int m = 0; m < 4; ++m)
#pragma unroll
    for (int n = 0; n < 4; ++n)
#pragma unroll
      for (int r = 0; r < 4; ++r) {
        int row = wr * 64 + m * 16 + hi * 4 + r;
        int col = wc * 64 + n * 16 + lo;
        gp[row * 128 + col] = acc[m][n][r];
      }
}

// ---------------- Gram via bf16 MFMA from fp32 U (fallback) ----------
__global__ __launch_bounds__(256) void gram_mfma_kernel(const float* __restrict__ U,
                                                        float* __restrict__ Gpart,
                                                        int kch) {
  int bx = blockIdx.x;
  int tile = bx % 3;
  int chunk = bx / 3;
  int ti = (tile == 2) ? 1 : 0;
  int tj = (tile == 0) ? 0 : 1;
  bool diag = (tile != 1);
  int t = threadIdx.x;
  int lane = t & 63, wave = t >> 6;
  int lo = lane & 15, hi = lane >> 4;
  int wr = wave >> 1, wc = wave & 1;
  __shared__ __align__(16) u16 lp[2][128 * 64];
  size_t kbase = (size_t)chunk * kch;
  f32x4 acc[4][4];
#pragma unroll
  for (int m = 0; m < 4; ++m)
#pragma unroll
    for (int n = 0; n < 4; ++n) acc[m][n] = (f32x4){0.f, 0.f, 0.f, 0.f};
  int nslots = diag ? 1024 : 2048;
  for (int k0 = 0; k0 < kch; k0 += 64) {
    for (int s = t; s < nslots; s += 256) {
      int panel = s >> 10;
      int sl = s & 1023;
      int row = sl >> 3, q = sl & 7;
      int grow = (panel ? tj : ti) * 128 + row;
      const float* src = U + (size_t)grow * Lflat + kbase + k0 + q * 8;
      float4 f0 = *(const float4*)src;
      float4 f1 = *(const float4*)(src + 4);
      union { short8b v; u16 u[8]; } pk;
      pk.u[0] = f2bf(f0.x); pk.u[1] = f2bf(f0.y); pk.u[2] = f2bf(f0.z); pk.u[3] = f2bf(f0.w);
      pk.u[4] = f2bf(f1.x); pk.u[5] = f2bf(f1.y); pk.u[6] = f2bf(f1.z); pk.u[7] = f2bf(f1.w);
      *(short8b*)(&lp[panel][row * 64 + ((q ^ (row & 7)) << 3)]) = pk.v;
    }
    __syncthreads();
#pragma unroll
    for (int ks = 0; ks < 2; ++ks) {
      short8b af[4], bfv[4];
#pragma unroll
      for (int m = 0; m < 4; ++m) {
        int row = wr * 64 + m * 16 + lo;
        af[m] = *(const short8b*)(&lp[0][row * 64 + (((ks * 4 + hi) ^ (row & 7)) << 3)]);
      }
      const u16* pb = diag ? lp[0] : lp[1];
#pragma unroll
      for (int n = 0; n < 4; ++n) {
        int row = wc * 64 + n * 16 + lo;
        bfv[n] = *(const short8b*)(&pb[row * 64 + (((ks * 4 + hi) ^ (row & 7)) << 3)]);
      }
#pragma unroll
      for (int m = 0; m < 4; ++m)
#pragma unroll
        for (int n = 0; n < 4; ++n)
          acc[m][n] = __builtin_amdgcn_mfma_f32_16x16x32_bf16(af[m], bfv[n], acc[m][n], 0, 0, 0);
    }
    __syncthreads();
  }
  float* gp = Gpart + (size_t)bx * 16384;
#pragma unroll
  for (int m = 0; m < 4; ++m)
#pragma unroll
    for (int n = 0; n < 4; ++n)
#pragma unroll
      for (int r = 0; r < 4; ++r) {
        int row = wr * 64 + m * 16 + hi * 4 + r;
        int col = wc * 64 + n * 16 + lo;
        gp[row * 128 + col] = acc[m][n][r];
      }
}

__global__ __launch_bounds__(256) void gram_reduce_kernel(const float* __restrict__ Gpart,
                                                          float* __restrict__ G,
                                                          int nchunks) {
  int tile = blockIdx.x % 3, seg = blockIdx.x / 3;
  int ti = (tile == 2) ? 1 : 0;
  int tj = (tile == 0) ? 0 : 1;
  int e = seg * 1024 + threadIdx.x * 4;
  float4 s = {0.f, 0.f, 0.f, 0.f};
  for (int ch = 0; ch < nchunks; ++ch) {
    float4 v = *(const float4*)(Gpart + ((size_t)(ch * 3 + tile)) * 16384 + e);
    s.x += v.x; s.y += v.y; s.z += v.z; s.w += v.w;
  }
  int row = e >> 7, col = e & 127;
  int gi = ti * 128 + row, gj = tj * 128 + col;
  G[gi * Cc + gj + 0] = s.x;
  G[gi * Cc + gj + 1] = s.y;
  G[gi * Cc + gj + 2] = s.z;
  G[gi * Cc + gj + 3] = s.w;
  if (tile == 1) {
    G[(gj + 0) * Cc + gi] = s.x;
    G[(gj + 1) * Cc + gi] = s.y;
    G[(gj + 2) * Cc + gi] = s.z;
    G[(gj + 3) * Cc + gi] = s.w;
  }
}

// ---------------- Au = S @ UT^T : clean bf16 GEMM (M=256, N=8192, K=4096) ----------
// grid (jt=128, bt=2). block tile: 128 b x 64 j; 4 waves, each 64b x 32j.
__global__ __launch_bounds__(256) void au_gemm_kernel(const u16* __restrict__ S,
                                                      const u16* __restrict__ UT,
                                                      float* __restrict__ Au,
                                                      float* __restrict__ SC) {
  int jt = blockIdx.x, bt = blockIdx.y;
  int t = threadIdx.x, lane = t & 63, wave = t >> 6;
  int lo = lane & 15, hi = lane >> 4;
  int wr = wave >> 1, wc = wave & 1;
  __shared__ __align__(16) u16 Sa[128 * 64];
  __shared__ __align__(16) u16 Ub[64 * 64];
  f32x4 acc[4][2];
#pragma unroll
  for (int m = 0; m < 4; ++m)
#pragma unroll
    for (int n = 0; n < 2; ++n) acc[m][n] = (f32x4){0.f, 0.f, 0.f, 0.f};
  int lrow = lane >> 3;
  int lchunk8 = ((lane & 7) ^ lrow) * 8;
  for (int k0 = 0; k0 < Nn; k0 += 64) {
#pragma unroll
    for (int q = 0; q < 4; ++q) {
      int row = wave * 32 + q * 8;
      gll16(S + (size_t)(bt * 128 + row + lrow) * Nn + k0 + lchunk8, &Sa[row * 64]);
    }
#pragma unroll
    for (int q = 0; q < 2; ++q) {
      int row = wave * 16 + q * 8;
      gll16(UT + (size_t)(jt * 64 + row + lrow) * Nn + k0 + lchunk8, &Ub[row * 64]);
    }
    __syncthreads();
#pragma unroll
    for (int ks = 0; ks < 2; ++ks) {
      int q = ks * 4 + hi;
      short8b af[4], bfv[2];
#pragma unroll
      for (int m = 0; m < 4; ++m) {
        int r = wr * 64 + m * 16 + lo;
        af[m] = *(const short8b*)(&Sa[r * 64 + ((q ^ (r & 7)) << 3)]);
      }
#pragma unroll
      for (int n = 0; n < 2; ++n) {
        int r = wc * 32 + n * 16 + lo;
        bfv[n] = *(const short8b*)(&Ub[r * 64 + ((q ^ (r & 7)) << 3)]);
      }
#pragma unroll
      for (int m = 0; m < 4; ++m)
#pragma unroll
        for (int n = 0; n < 2; ++n)
          acc[m][n] = __builtin_amdgcn_mfma_f32_16x16x32_bf16(af[m], bfv[n], acc[m][n], 0, 0, 0);
    }
    __syncthreads();
  }
  int c = jt * 2 + wc;
#pragma unroll
  for (int m = 0; m < 4; ++m)
#pragma unroll
    for (int rr = 0; rr < 4; ++rr) {
      int b = bt * 128 + wr * 64 + m * 16 + hi * 4 + rr;
      float a0 = acc[m][0][rr], a1 = acc[m][1][rr];
      Au[((size_t)b * Cc + c) * Rr + lo]      = a0;
      Au[((size_t)b * Cc + c) * Rr + 16 + lo] = a1;
      float sq = a0 * a0 + a1 * a1;
      sq += __shfl_xor(sq, 1, 64);
      sq += __shfl_xor(sq, 2, 64);
      sq += __shfl_xor(sq, 4, 64);
      sq += __shfl_xor(sq, 8, 64);
      if (lo == 0) SC[(size_t)b * Cc + c] = sq * (1.f / (Kk * Rr));
    }
}

// ---------------- Au fallback (fp32 U, in-kernel transpose) ----------------
__global__ __launch_bounds__(256) void au_mfma_kernel(const float* __restrict__ U,
                                                      const u16* __restrict__ S,
                                                      float* __restrict__ Au,
                                                      float* __restrict__ SC) {
  int c = blockIdx.x, mb = blockIdx.y;
  int t = threadIdx.x;
  int lane = t & 63, wave = t >> 6;
  int lo = lane & 15, hi = lane >> 4;
  __shared__ __align__(16) u16 Ss[128 * 64];
  __shared__ __align__(16) u16 Us[32 * 64];
  f32x4 acc[2][2];
#pragma unroll
  for (int m = 0; m < 2; ++m)
#pragma unroll
    for (int n = 0; n < 2; ++n) acc[m][n] = (f32x4){0.f, 0.f, 0.f, 0.f};
  const float* Uc = U + (size_t)c * Lflat;
  for (int k0 = 0; k0 < Nn; k0 += 64) {
    for (int s = t; s < 1024; s += 256) {
      int row = s >> 3, q = s & 7;
      short8b v = *(const short8b*)(S + (size_t)(mb * 128 + row) * Nn + k0 + q * 8);
      *(short8b*)(&Ss[row * 64 + ((q ^ (row & 7)) << 3)]) = v;
    }
    for (int s = t; s < 512; s += 256) {
      int kk = s >> 3, rq = s & 7;
      float4 f = *(const float4*)(Uc + (size_t)(k0 + kk) * Rr + rq * 4);
      float fv[4] = {f.x, f.y, f.z, f.w};
#pragma unroll
      for (int j = 0; j < 4; ++j) {
        int r = rq * 4 + j;
        Us[r * 64 + (((kk >> 3) ^ (r & 7)) << 3) + (kk & 7)] = f2bf(fv[j]);
      }
    }
    __syncthreads();
#pragma unroll
    for (int kf = 0; kf < 2; ++kf) {
      int q = kf * 4 + hi;
      short8b af[2], bf[2];
#pragma unroll
      for (int m = 0; m < 2; ++m) {
        int row = wave * 32 + m * 16 + lo;
        af[m] = *(const short8b*)(&Ss[row * 64 + ((q ^ (row & 7)) << 3)]);
      }
#pragma unroll
      for (int n = 0; n < 2; ++n) {
        int row = n * 16 + lo;
        bf[n] = *(const short8b*)(&Us[row * 64 + ((q ^ (row & 7)) << 3)]);
      }
#pragma unroll
      for (int m = 0; m < 2; ++m)
#pragma unroll
        for (int n = 0; n < 2; ++n)
          acc[m][n] = __builtin_amdgcn_mfma_f32_16x16x32_bf16(af[m], bf[n], acc[m][n], 0, 0, 0);
    }
    __syncthreads();
  }
#pragma unroll
  for (int m = 0; m < 2; ++m) {
#pragma unroll
    for (int r = 0; r < 4; ++r) {
      int b = mb * 128 + wave * 32 + m * 16 + hi * 4 + r;
#pragma unroll
      for (int n = 0; n < 2; ++n) {
        int rr = n * 16 + lo;
        Au[((size_t)b * Cc + c) * Rr + rr] = acc[m][n][r];
      }
      float sq = acc[m][0][r] * acc[m][0][r] + acc[m][1][r] * acc[m][1][r];
      sq += __shfl_xor(sq, 1, 64);
      sq += __shfl_xor(sq, 2, 64);
      sq += __shfl_xor(sq, 4, 64);
      sq += __shfl_xor(sq, 8, 64);
      if (lo == 0) SC[(size_t)b * Cc + c] = sq * (1.f / (Kk * Rr));
    }
  }
}

// ---------------- match scores + softmax -> beta ----------------
__global__ __launch_bounds__(256) void softmax_kernel(const float* __restrict__ SWp,
                                                      const float* __restrict__ SC,
                                                      const float* __restrict__ span_t,
                                                      const float* __restrict__ PS,
                                                      float* __restrict__ beta) {
  int b = blockIdx.x, t = threadIdx.x;
  float span_norm = fminf(fmaxf(span_t[b] * (1.f / 20.f), 0.f), 1.f);
  float psn = 1.f / (1.f + expf(-PS[t]));
  float m = 0.f;
#pragma unroll
  for (int kc = 0; kc < SKW; ++kc) m += SWp[(size_t)kc * (Bb * Cc) + b * Cc + t];
  m += SC[b * Cc + t] - 0.3f * fabsf(span_norm - psn);
  __shared__ float redM[4], redS[4];
  float mx = m;
#pragma unroll
  for (int off = 32; off; off >>= 1) mx = fmaxf(mx, __shfl_xor(mx, off, 64));
  if ((t & 63) == 0) redM[t >> 6] = mx;
  __syncthreads();
  mx = fmaxf(fmaxf(redM[0], redM[1]), fmaxf(redM[2], redM[3]));
  float e = expf(m - mx);
  float s = e;
#pragma unroll
  for (int off = 32; off; off >>= 1) s += __shfl_xor(s, off, 64);
  if ((t & 63) == 0) redS[t >> 6] = s;
  __syncthreads();
  s = redS[0] + redS[1] + redS[2] + redS[3];
  beta[b * Cc + t] = e / s;
}

// ---------------- residual ----------------
__global__ __launch_bounds__(256) void final_kernel(const float* __restrict__ beta,
                                                    const float* __restrict__ G,
                                                    const float* __restrict__ Au,
                                                    const float* __restrict__ tval,
                                                    float* __restrict__ out) {
  int b = blockIdx.x, t = threadIdx.x;
  __shared__ float sb[Cc];
  __shared__ float au2[8][32];
  __shared__ float redA[4], redB[4];
  sb[t] = beta[b * Cc + t];
  __syncthreads();
  float w = 0.f;
  for (int c = 0; c < Cc; ++c) w = fmaf(sb[c], G[c * Cc + t], w);
  float pr = sb[t] * w;
  int r = t & 31, g = t >> 5;
  float p = 0.f;
#pragma unroll 8
  for (int cc = 0; cc < 32; ++cc) {
    int c = cc * 8 + g;
    p = fmaf(sb[c], Au[((size_t)b * Cc + c) * Rr + r], p);
  }
  au2[g][r] = p;
  float h = (t < Kk) ? tval[b * Kk + t] * tval[b * Kk + t] : 0.f;
  float x = pr;
#pragma unroll
  for (int off = 32; off; off >>= 1) x += __shfl_xor(x, off, 64);
  if ((t & 63) == 0) redA[t >> 6] = x;
  float y = h;
#pragma unroll
  for (int off = 32; off; off >>= 1) y += __shfl_xor(y, off, 64);
  if ((t & 63) == 0) redB[t >> 6] = y;
  __syncthreads();
  float recon = (redA[0] + redA[1] + redA[2] + redA[3]) * (1.f / 4096.f);
  float mhat  = (redB[0] + redB[1] + redB[2] + redB[3]) * (1.f / 128.f);
  float cr = 0.f;
  if (t < 32) {
    float a2 = 0.f;
#pragma unroll
    for (int gg = 0; gg < 8; ++gg) a2 += au2[gg][t];
    cr = a2 * a2;
  }
#pragma unroll
  for (int off = 16; off; off >>= 1) cr += __shfl_xor(cr, off, 64);
  if (t == 0) {
    cr *= (1.f / 4096.f);
    float res = mhat - 2.f * cr + recon;
    res = fminf(fmaxf(res, 0.f), 10000.f);
    out[b] = res;
  }
}

extern "C" void kernel_launch(void* const* d_in, const int* in_sizes, int n_in,
                              void* d_out, int out_size, void* d_ws, size_t ws_size,
                              hipStream_t stream) {
  const float* A      = (const float*)d_in[0];
  const float* span_t = (const float*)d_in[1];
  const float* W      = (const float*)d_in[2];
  const float* U      = (const float*)d_in[3];
  const float* PS     = (const float*)d_in[4];
  float* out = (float*)d_out;

  char* p = (char*)d_ws;
  int*   tidx = (int*)p;   p += (size_t)Bb * Kk * 4;
  float* tval = (float*)p; p += (size_t)Bb * Kk * 4;
  float* SWp  = (float*)p; p += (size_t)SKW * Bb * Cc * 4;
  float* SC   = (float*)p; p += (size_t)Bb * Cc * 4;
  float* beta = (float*)p; p += (size_t)Bb * Cc * 4;
  float* G    = (float*)p; p += (size_t)Cc * Cc * 4;
  u16*   S    = (u16*)p;   p += (size_t)Bb * Nn * 2;
  float* Au   = (float*)p; p += (size_t)Bb * Cc * Rr * 4;
  size_t fixed = (size_t)(p - (char*)d_ws);
  size_t UTsz = (size_t)Cc * Lflat * 2;                       // 67 MB
  bool planA = ws_size >= fixed + UTsz + (size_t)3 * 8 * 16384 * 4;

  topk_kernel<<<dim3(Bb), dim3(256), 0, stream>>>(A, tidx, tval);
  scatter_kernel<<<dim3(Bb), dim3(256), 0, stream>>>(tidx, tval, S);
  scorew_mfma_kernel<<<dim3(4, 4, SKW), dim3(256), 0, stream>>>(A, W, SWp);

  if (planA) {
    u16* UT = (u16*)p; p += UTsz;
    size_t used = fixed + UTsz;
    int nchunks = 64;
    while (nchunks > 8 && used + (size_t)(3 * nchunks) * 16384 * 4 > ws_size) nchunks >>= 1;
    float* Gpart = (float*)p;
    u2t_kernel<<<dim3(Cc, 8), dim3(256), 0, stream>>>(U, UT);
    gram_bf16_kernel<<<dim3(3 * nchunks), dim3(256), 0, stream>>>(UT, Gpart, Lflat / nchunks);
    gram_reduce_kernel<<<dim3(48), dim3(256), 0, stream>>>(Gpart, G, nchunks);
    au_gemm_kernel<<<dim3(128, 2), dim3(256), 0, stream>>>(S, UT, Au, SC);
  } else {
    int nchunks = 64;
    while (nchunks > 8 && fixed + (size_t)(3 * nchunks) * 16384 * 4 > ws_size) nchunks >>= 1;
    float* Gpart = (float*)p;
    gram_mfma_kernel<<<dim3(3 * nchunks), dim3(256), 0, stream>>>(U, Gpart, Lflat / nchunks);
    gram_reduce_kernel<<<dim3(48), dim3(256), 0, stream>>>(Gpart, G, nchunks);
    au_mfma_kernel<<<dim3(Cc, 2), dim3(256), 0, stream>>>(U, S, Au, SC);
  }

  softmax_kernel<<<dim3(Bb), dim3(256), 0, stream>>>(SWp, SC, span_t, PS, beta);
  final_kernel<<<dim3(Bb), dim3(256), 0, stream>>>(beta, G, Au, tval, out);
}

// Round 5
// 193.232 us; speedup vs baseline: 4.9373x; 1.0955x over previous
//
#include <hip/hip_runtime.h>
#include <math.h>

#define Bb 256
#define Nn 4096
#define Cc 256
#define Rr 32
#define Kk 128
#define Lflat (Nn * Rr)          // 131072
#define LN2f 0.6931471805599453f
#define SKW 16                   // split-K factor for scorew MFMA

typedef unsigned short u16;
typedef __attribute__((ext_vector_type(8))) short short8b;  // 8 bf16
typedef __attribute__((ext_vector_type(4))) float f32x4;

typedef __attribute__((address_space(1))) const void* gas_t;
typedef __attribute__((address_space(3))) void* las_t;
__device__ __forceinline__ void gll16(const void* g, void* l) {
  __builtin_amdgcn_global_load_lds((gas_t)g, (las_t)l, 16, 0, 0);
}

__device__ inline u16 f2bf(float x) {            // RNE float->bf16
  unsigned u = __float_as_uint(x);
  unsigned r = (u + 0x7fffu + ((u >> 16) & 1u)) >> 16;
  return (u16)r;
}

// ---- monotone float<->uint mapping ----
__device__ inline unsigned f2u(float f) {
  unsigned b = __float_as_uint(f);
  return (b & 0x80000000u) ? ~b : (b | 0x80000000u);
}
__device__ inline float u2f(unsigned u) {
  unsigned b = (u & 0x80000000u) ? (u ^ 0x80000000u) : ~u;
  return __uint_as_float(b);
}

// ---------------- top-k via 8-bit radix select; fused scatter + norm_Mhat ----------
// Elements live in registers (16/thread). 4 digit passes, per-wave histograms.
__global__ __launch_bounds__(256) void topk_kernel(const float* __restrict__ A,
                                                   u16* __restrict__ S,
                                                   float* __restrict__ mhat) {
  int b = blockIdx.x, t = threadIdx.x;
  int lane = t & 63, wave = t >> 6;
  const float* row = A + (size_t)b * Nn;
  u16* Srow = S + (size_t)b * Nn;
  short8b z = {0, 0, 0, 0, 0, 0, 0, 0};
  *(short8b*)(Srow + t * 16) = z;                 // zero S row (ordered by barriers below)
  *(short8b*)(Srow + t * 16 + 8) = z;

  float f[16]; unsigned u[16];
#pragma unroll
  for (int j = 0; j < 4; ++j) {
    float4 v = ((const float4*)row)[j * 256 + t];
    f[j * 4 + 0] = v.x; f[j * 4 + 1] = v.y; f[j * 4 + 2] = v.z; f[j * 4 + 3] = v.w;
  }
#pragma unroll
  for (int j = 0; j < 16; ++j) u[j] = f2u(f[j]);

  __shared__ int hist[4][256];
  __shared__ int sufs[257];
  __shared__ int wtot[4];
  __shared__ int s_d, s_cg;
  __shared__ int s_eqidx[256];
  __shared__ int s_eqcnt;
  __shared__ float redQ[4];
  if (t == 0) s_eqcnt = 0;

  unsigned T = 0u;
  int cntG = 0;
#pragma unroll
  for (int p = 3; p >= 0; --p) {
    hist[0][t] = 0; hist[1][t] = 0; hist[2][t] = 0; hist[3][t] = 0;
    __syncthreads();
    unsigned mh = (p == 3) ? 0u : (0xFFFFFFFFu << (8 * (p + 1)));
    int* hw = hist[wave];
#pragma unroll
    for (int j = 0; j < 16; ++j)
      if (((u[j] ^ T) & mh) == 0) atomicAdd(&hw[(u[j] >> (8 * p)) & 255], 1);
    __syncthreads();
    int v = hist[0][t] + hist[1][t] + hist[2][t] + hist[3][t];
#pragma unroll
    for (int off = 1; off < 64; off <<= 1) {      // wave suffix-inclusive scan
      int tmp = __shfl_down(v, off, 64);
      if (lane + off < 64) v += tmp;
    }
    if (lane == 0) wtot[wave] = v;
    __syncthreads();
    for (int w2 = wave + 1; w2 < 4; ++w2) v += wtot[w2];
    sufs[t] = v;
    if (t == 0) sufs[256] = 0;
    __syncthreads();
    int nxt = sufs[t + 1];
    if ((cntG + v >= Kk) && (cntG + nxt < Kk)) { s_d = t; s_cg = cntG + nxt; }
    __syncthreads();
    T |= (unsigned)s_d << (8 * p);
    cntG = s_cg;
    __syncthreads();
  }
  // T = K-th largest (u-order); cntG = count(u > T) < K.
  float sq = 0.f;
#pragma unroll
  for (int j = 0; j < 16; ++j) {
    int idx = (j >> 2) * 1024 + t * 4 + (j & 3);
    if (u[j] > T) {
      Srow[idx] = f2bf(f[j]);
      sq += f[j] * f[j];
    } else if (u[j] == T) {
      int q2 = atomicAdd(&s_eqcnt, 1);
      if (q2 < 256) s_eqidx[q2] = idx;
    }
  }
#pragma unroll
  for (int off = 32; off; off >>= 1) sq += __shfl_xor(sq, off, 64);
  if (lane == 0) redQ[wave] = sq;
  __syncthreads();
  if (t == 0) {                                   // tie path: smallest indices (jax order)
    float tv = u2f(T);
    u16 tb = f2bf(tv);
    int need = Kk - cntG;
    int eq = min(s_eqcnt, 256);
    for (int s2 = 0; s2 < need; ++s2) {
      int best = 0x7fffffff, bi = 0;
      for (int jj = 0; jj < eq; ++jj)
        if (s_eqidx[jj] < best) { best = s_eqidx[jj]; bi = jj; }
      Srow[best] = tb;
      s_eqidx[bi] = 0x7fffffff;
    }
    mhat[b] = redQ[0] + redQ[1] + redQ[2] + redQ[3] + (float)need * tv * tv;
  }
}

// ---------------- u2t: U[c][n][r] fp32 -> UT[c][r][n] bf16, LDS-free ---------------
__global__ __launch_bounds__(256) void u2t_kernel(const float* __restrict__ U,
                                                  u16* __restrict__ UT) {
  int c = blockIdx.x, nb = blockIdx.y, t = threadIdx.x;
  int r = t & 31, nblk = t >> 5;                  // 8 n-chunks of 8
  const float* Uc = U + (size_t)c * Lflat;
  u16* UTc = UT + (size_t)c * Lflat;
  for (int it = 0; it < 8; ++it) {
    int n0 = nb * 512 + it * 64 + nblk * 8;
    union { short8b v; u16 s[8]; } pk;
#pragma unroll
    for (int i = 0; i < 8; ++i)
      pk.s[i] = f2bf(Uc[(size_t)(n0 + i) * Rr + r]);   // lanes 0-31: consecutive floats
    *(short8b*)(UTc + (size_t)r * Nn + n0) = pk.v;
  }
}

// ---------------- score_w via bf16 MFMA, softplus fused in staging -----------------
__global__ __launch_bounds__(256) void scorew_mfma_kernel(const float* __restrict__ Ag,
                                                          const float* __restrict__ W,
                                                          float* __restrict__ SWp) {
  int ct = blockIdx.x, mt = blockIdx.y, ks = blockIdx.z;
  int t = threadIdx.x;
  int lane = t & 63, wave = t >> 6;
  int lo = lane & 15, hi = lane >> 4;
  int wr = wave >> 1, wc = wave & 1;
  __shared__ __align__(16) u16 As[64 * 64];
  __shared__ __align__(16) u16 Ws[64 * 64];
  f32x4 acc[2][2];
#pragma unroll
  for (int m = 0; m < 2; ++m)
#pragma unroll
    for (int n = 0; n < 2; ++n) acc[m][n] = (f32x4){0.f, 0.f, 0.f, 0.f};
  int kbase = ks * (Nn / SKW);
  for (int k0 = 0; k0 < Nn / SKW; k0 += 64) {
    for (int s = t; s < 1024; s += 256) {
      int panel = s >> 9;
      int sl = s & 511;
      int row = sl >> 3, q = sl & 7;
      union { short8b v; u16 u[8]; } pk;
      if (panel == 0) {
        const float* src = Ag + (size_t)(mt * 64 + row) * Nn + kbase + k0 + q * 8;
        float4 f0 = *(const float4*)src, f1 = *(const float4*)(src + 4);
        pk.u[0] = f2bf(f0.x); pk.u[1] = f2bf(f0.y); pk.u[2] = f2bf(f0.z); pk.u[3] = f2bf(f0.w);
        pk.u[4] = f2bf(f1.x); pk.u[5] = f2bf(f1.y); pk.u[6] = f2bf(f1.z); pk.u[7] = f2bf(f1.w);
        *(short8b*)(&As[row * 64 + ((q ^ (row & 7)) << 3)]) = pk.v;
      } else {
        const float* src = W + (size_t)(ct * 64 + row) * Nn + kbase + k0 + q * 8;
        float4 f0 = *(const float4*)src, f1 = *(const float4*)(src + 4);
        float w[8] = {f0.x, f0.y, f0.z, f0.w, f1.x, f1.y, f1.z, f1.w};
#pragma unroll
        for (int j = 0; j < 8; ++j)
          pk.u[j] = f2bf(fmaxf(w[j], 0.f) + log1pf(expf(-fabsf(w[j]))) - LN2f);
        *(short8b*)(&Ws[row * 64 + ((q ^ (row & 7)) << 3)]) = pk.v;
      }
    }
    __syncthreads();
#pragma unroll
    for (int kf = 0; kf < 2; ++kf) {
      int q = kf * 4 + hi;
      short8b af[2], bf[2];
#pragma unroll
      for (int m = 0; m < 2; ++m) {
        int row = wr * 32 + m * 16 + lo;
        af[m] = *(const short8b*)(&As[row * 64 + ((q ^ (row & 7)) << 3)]);
      }
#pragma unroll
      for (int n = 0; n < 2; ++n) {
        int row = wc * 32 + n * 16 + lo;
        bf[n] = *(const short8b*)(&Ws[row * 64 + ((q ^ (row & 7)) << 3)]);
      }
#pragma unroll
      for (int m = 0; m < 2; ++m)
#pragma unroll
        for (int n = 0; n < 2; ++n)
          acc[m][n] = __builtin_amdgcn_mfma_f32_16x16x32_bf16(af[m], bf[n], acc[m][n], 0, 0, 0);
    }
    __syncthreads();
  }
  float* o = SWp + (size_t)ks * (Bb * Cc);
#pragma unroll
  for (int m = 0; m < 2; ++m)
#pragma unroll
    for (int n = 0; n < 2; ++n)
#pragma unroll
      for (int r = 0; r < 4; ++r) {
        int b = mt * 64 + wr * 32 + m * 16 + hi * 4 + r;
        int c = ct * 64 + wc * 32 + n * 16 + lo;
        o[(size_t)b * Cc + c] = acc[m][n][r];
      }
}

// ---------------- Gram from bf16 UT via global_load_lds ----------------
__global__ __launch_bounds__(256) void gram_bf16_kernel(const u16* __restrict__ UT,
                                                        float* __restrict__ Gpart,
                                                        int kch) {
  int bx = blockIdx.x;
  int tile = bx % 3, chunk = bx / 3;
  int ti = (tile == 2) ? 1 : 0;
  int tj = (tile == 0) ? 0 : 1;
  bool diag = (tile != 1);
  int t = threadIdx.x, lane = t & 63, wave = t >> 6;
  int lo = lane & 15, hi = lane >> 4;
  int wr = wave >> 1, wc = wave & 1;
  __shared__ __align__(16) u16 lp[2][128 * 64];
  f32x4 acc[4][4];
#pragma unroll
  for (int m = 0; m < 4; ++m)
#pragma unroll
    for (int n = 0; n < 4; ++n) acc[m][n] = (f32x4){0.f, 0.f, 0.f, 0.f};
  int lrow = lane >> 3;
  int lchunk8 = ((lane & 7) ^ lrow) * 8;          // source-side swizzle (rule #21)
  size_t kbase = (size_t)chunk * kch;
  for (int k0 = 0; k0 < kch; k0 += 64) {
    size_t kg = kbase + k0;
#pragma unroll
    for (int q = 0; q < 4; ++q) {
      int row = wave * 32 + q * 8;
      gll16(UT + (size_t)(ti * 128 + row + lrow) * Lflat + kg + lchunk8, &lp[0][row * 64]);
    }
    if (!diag) {
#pragma unroll
      for (int q = 0; q < 4; ++q) {
        int row = wave * 32 + q * 8;
        gll16(UT + (size_t)(tj * 128 + row + lrow) * Lflat + kg + lchunk8, &lp[1][row * 64]);
      }
    }
    __syncthreads();
#pragma unroll
    for (int ks = 0; ks < 2; ++ks) {
      short8b af[4], bfv[4];
#pragma unroll
      for (int m = 0; m < 4; ++m) {
        int row = wr * 64 + m * 16 + lo;
        af[m] = *(const short8b*)(&lp[0][row * 64 + (((ks * 4 + hi) ^ (row & 7)) << 3)]);
      }
      const u16* pb = diag ? lp[0] : lp[1];
#pragma unroll
      for (int n = 0; n < 4; ++n) {
        int row = wc * 64 + n * 16 + lo;
        bfv[n] = *(const short8b*)(&pb[row * 64 + (((ks * 4 + hi) ^ (row & 7)) << 3)]);
      }
#pragma unroll
      for (int m = 0; m < 4; ++m)
#pragma unroll
        for (int n = 0; n < 4; ++n)
          acc[m][n] = __builtin_amdgcn_mfma_f32_16x16x32_bf16(af[m], bfv[n], acc[m][n], 0, 0, 0);
    }
    __syncthreads();
  }
  float* gp = Gpart + (size_t)bx * 16384;
#pragma unroll
  for (int m = 0; m < 4; ++m)
#pragma unroll
    for (int n = 0; n < 4; ++n)
#pragma unroll
      for (int r = 0; r < 4; ++r) {
        int row = wr * 64 + m * 16 + hi * 4 + r;
        int col = wc * 64 + n * 16 + lo;
        gp[row * 128 + col] = acc[m][n][r];
      }
}

// ---------------- Gram via bf16 MFMA from fp32 U (fallback) ----------
__global__ __launch_bounds__(256) void gram_mfma_kernel(const float* __restrict__ U,
                                                        float* __restrict__ Gpart,
                                                        int kch) {
  int bx = blockIdx.x;
  int tile = bx % 3;
  int chunk = bx / 3;
  int ti = (tile == 2) ? 1 : 0;
  int tj = (tile == 0) ? 0 : 1;
  bool diag = (tile != 1);
  int t = threadIdx.x;
  int lane = t & 63, wave = t >> 6;
  int lo = lane & 15, hi = lane >> 4;
  int wr = wave >> 1, wc = wave & 1;
  __shared__ __align__(16) u16 lp[2][128 * 64];
  size_t kbase = (size_t)chunk * kch;
  f32x4 acc[4][4];
#pragma unroll
  for (int m = 0; m < 4; ++m)
#pragma unroll
    for (int n = 0; n < 4; ++n) acc[m][n] = (f32x4){0.f, 0.f, 0.f, 0.f};
  int nslots = diag ? 1024 : 2048;
  for (int k0 = 0; k0 < kch; k0 += 64) {
    for (int s = t; s < nslots; s += 256) {
      int panel = s >> 10;
      int sl = s & 1023;
      int row = sl >> 3, q = sl & 7;
      int grow = (panel ? tj : ti) * 128 + row;
      const float* src = U + (size_t)grow * Lflat + kbase + k0 + q * 8;
      float4 f0 = *(const float4*)src;
      float4 f1 = *(const float4*)(src + 4);
      union { short8b v; u16 u[8]; } pk;
      pk.u[0] = f2bf(f0.x); pk.u[1] = f2bf(f0.y); pk.u[2] = f2bf(f0.z); pk.u[3] = f2bf(f0.w);
      pk.u[4] = f2bf(f1.x); pk.u[5] = f2bf(f1.y); pk.u[6] = f2bf(f1.z); pk.u[7] = f2bf(f1.w);
      *(short8b*)(&lp[panel][row * 64 + ((q ^ (row & 7)) << 3)]) = pk.v;
    }
    __syncthreads();
#pragma unroll
    for (int ks = 0; ks < 2; ++ks) {
      short8b af[4], bfv[4];
#pragma unroll
      for (int m = 0; m < 4; ++m) {
        int row = wr * 64 + m * 16 + lo;
        af[m] = *(const short8b*)(&lp[0][row * 64 + (((ks * 4 + hi) ^ (row & 7)) << 3)]);
      }
      const u16* pb = diag ? lp[0] : lp[1];
#pragma unroll
      for (int n = 0; n < 4; ++n) {
        int row = wc * 64 + n * 16 + lo;
        bfv[n] = *(const short8b*)(&pb[row * 64 + (((ks * 4 + hi) ^ (row & 7)) << 3)]);
      }
#pragma unroll
      for (int m = 0; m < 4; ++m)
#pragma unroll
        for (int n = 0; n < 4; ++n)
          acc[m][n] = __builtin_amdgcn_mfma_f32_16x16x32_bf16(af[m], bfv[n], acc[m][n], 0, 0, 0);
    }
    __syncthreads();
  }
  float* gp = Gpart + (size_t)bx * 16384;
#pragma unroll
  for (int m = 0; m < 4; ++m)
#pragma unroll
    for (int n = 0; n < 4; ++n)
#pragma unroll
      for (int r = 0; r < 4; ++r) {
        int row = wr * 64 + m * 16 + hi * 4 + r;
        int col = wc * 64 + n * 16 + lo;
        gp[row * 128 + col] = acc[m][n][r];
      }
}

__global__ __launch_bounds__(256) void gram_reduce_kernel(const float* __restrict__ Gpart,
                                                          float* __restrict__ G,
                                                          int nchunks) {
  int tile = blockIdx.x % 3, seg = blockIdx.x / 3;
  int ti = (tile == 2) ? 1 : 0;
  int tj = (tile == 0) ? 0 : 1;
  int e = seg * 1024 + threadIdx.x * 4;
  float4 s = {0.f, 0.f, 0.f, 0.f};
  for (int ch = 0; ch < nchunks; ++ch) {
    float4 v = *(const float4*)(Gpart + ((size_t)(ch * 3 + tile)) * 16384 + e);
    s.x += v.x; s.y += v.y; s.z += v.z; s.w += v.w;
  }
  int row = e >> 7, col = e & 127;
  int gi = ti * 128 + row, gj = tj * 128 + col;
  G[gi * Cc + gj + 0] = s.x;
  G[gi * Cc + gj + 1] = s.y;
  G[gi * Cc + gj + 2] = s.z;
  G[gi * Cc + gj + 3] = s.w;
  if (tile == 1) {
    G[(gj + 0) * Cc + gi] = s.x;
    G[(gj + 1) * Cc + gi] = s.y;
    G[(gj + 2) * Cc + gi] = s.z;
    G[(gj + 3) * Cc + gi] = s.w;
  }
}

// ---------------- Au = S @ UT^T : bf16 GEMM (M=256, N=8192, K=4096) ----------------
__global__ __launch_bounds__(256) void au_gemm_kernel(const u16* __restrict__ S,
                                                      const u16* __restrict__ UT,
                                                      float* __restrict__ Au,
                                                      float* __restrict__ SC) {
  int jt = blockIdx.x, bt = blockIdx.y;
  int t = threadIdx.x, lane = t & 63, wave = t >> 6;
  int lo = lane & 15, hi = lane >> 4;
  int wr = wave >> 1, wc = wave & 1;
  __shared__ __align__(16) u16 Sa[128 * 64];
  __shared__ __align__(16) u16 Ub[64 * 64];
  f32x4 acc[4][2];
#pragma unroll
  for (int m = 0; m < 4; ++m)
#pragma unroll
    for (int n = 0; n < 2; ++n) acc[m][n] = (f32x4){0.f, 0.f, 0.f, 0.f};
  int lrow = lane >> 3;
  int lchunk8 = ((lane & 7) ^ lrow) * 8;
  for (int k0 = 0; k0 < Nn; k0 += 64) {
#pragma unroll
    for (int q = 0; q < 4; ++q) {
      int row = wave * 32 + q * 8;
      gll16(S + (size_t)(bt * 128 + row + lrow) * Nn + k0 + lchunk8, &Sa[row * 64]);
    }
#pragma unroll
    for (int q = 0; q < 2; ++q) {
      int row = wave * 16 + q * 8;
      gll16(UT + (size_t)(jt * 64 + row + lrow) * Nn + k0 + lchunk8, &Ub[row * 64]);
    }
    __syncthreads();
#pragma unroll
    for (int ks = 0; ks < 2; ++ks) {
      int q = ks * 4 + hi;
      short8b af[4], bfv[2];
#pragma unroll
      for (int m = 0; m < 4; ++m) {
        int r = wr * 64 + m * 16 + lo;
        af[m] = *(const short8b*)(&Sa[r * 64 + ((q ^ (r & 7)) << 3)]);
      }
#pragma unroll
      for (int n = 0; n < 2; ++n) {
        int r = wc * 32 + n * 16 + lo;
        bfv[n] = *(const short8b*)(&Ub[r * 64 + ((q ^ (r & 7)) << 3)]);
      }
#pragma unroll
      for (int m = 0; m < 4; ++m)
#pragma unroll
        for (int n = 0; n < 2; ++n)
          acc[m][n] = __builtin_amdgcn_mfma_f32_16x16x32_bf16(af[m], bfv[n], acc[m][n], 0, 0, 0);
    }
    __syncthreads();
  }
  int c = jt * 2 + wc;
#pragma unroll
  for (int m = 0; m < 4; ++m)
#pragma unroll
    for (int rr = 0; rr < 4; ++rr) {
      int b = bt * 128 + wr * 64 + m * 16 + hi * 4 + rr;
      float a0 = acc[m][0][rr], a1 = acc[m][1][rr];
      Au[((size_t)b * Cc + c) * Rr + lo]      = a0;
      Au[((size_t)b * Cc + c) * Rr + 16 + lo] = a1;
      float sq = a0 * a0 + a1 * a1;
      sq += __shfl_xor(sq, 1, 64);
      sq += __shfl_xor(sq, 2, 64);
      sq += __shfl_xor(sq, 4, 64);
      sq += __shfl_xor(sq, 8, 64);
      if (lo == 0) SC[(size_t)b * Cc + c] = sq * (1.f / (Kk * Rr));
    }
}

// ---------------- Au fallback (fp32 U, in-kernel transpose) ----------------
__global__ __launch_bounds__(256) void au_mfma_kernel(const float* __restrict__ U,
                                                      const u16* __restrict__ S,
                                                      float* __restrict__ Au,
                                                      float* __restrict__ SC) {
  int c = blockIdx.x, mb = blockIdx.y;
  int t = threadIdx.x;
  int lane = t & 63, wave = t >> 6;
  int lo = lane & 15, hi = lane >> 4;
  __shared__ __align__(16) u16 Ss[128 * 64];
  __shared__ __align__(16) u16 Us[32 * 64];
  f32x4 acc[2][2];
#pragma unroll
  for (int m = 0; m < 2; ++m)
#pragma unroll
    for (int n = 0; n < 2; ++n) acc[m][n] = (f32x4){0.f, 0.f, 0.f, 0.f};
  const float* Uc = U + (size_t)c * Lflat;
  for (int k0 = 0; k0 < Nn; k0 += 64) {
    for (int s = t; s < 1024; s += 256) {
      int row = s >> 3, q = s & 7;
      short8b v = *(const short8b*)(S + (size_t)(mb * 128 + row) * Nn + k0 + q * 8);
      *(short8b*)(&Ss[row * 64 + ((q ^ (row & 7)) << 3)]) = v;
    }
    for (int s = t; s < 512; s += 256) {
      int kk = s >> 3, rq = s & 7;
      float4 f = *(const float4*)(Uc + (size_t)(k0 + kk) * Rr + rq * 4);
      float fv[4] = {f.x, f.y, f.z, f.w};
#pragma unroll
      for (int j = 0; j < 4; ++j) {
        int r = rq * 4 + j;
        Us[r * 64 + (((kk >> 3) ^ (r & 7)) << 3) + (kk & 7)] = f2bf(fv[j]);
      }
    }
    __syncthreads();
#pragma unroll
    for (int kf = 0; kf < 2; ++kf) {
      int q = kf * 4 + hi;
      short8b af[2], bf[2];
#pragma unroll
      for (int m = 0; m < 2; ++m) {
        int row = wave * 32 + m * 16 + lo;
        af[m] = *(const short8b*)(&Ss[row * 64 + ((q ^ (row & 7)) << 3)]);
      }
#pragma unroll
      for (int n = 0; n < 2; ++n) {
        int row = n * 16 + lo;
        bf[n] = *(const short8b*)(&Us[row * 64 + ((q ^ (row & 7)) << 3)]);
      }
#pragma unroll
      for (int m = 0; m < 2; ++m)
#pragma unroll
        for (int n = 0; n < 2; ++n)
          acc[m][n] = __builtin_amdgcn_mfma_f32_16x16x32_bf16(af[m], bf[n], acc[m][n], 0, 0, 0);
    }
    __syncthreads();
  }
#pragma unroll
  for (int m = 0; m < 2; ++m) {
#pragma unroll
    for (int r = 0; r < 4; ++r) {
      int b = mb * 128 + wave * 32 + m * 16 + hi * 4 + r;
#pragma unroll
      for (int n = 0; n < 2; ++n) {
        int rr = n * 16 + lo;
        Au[((size_t)b * Cc + c) * Rr + rr] = acc[m][n][r];
      }
      float sq = acc[m][0][r] * acc[m][0][r] + acc[m][1][r] * acc[m][1][r];
      sq += __shfl_xor(sq, 1, 64);
      sq += __shfl_xor(sq, 2, 64);
      sq += __shfl_xor(sq, 4, 64);
      sq += __shfl_xor(sq, 8, 64);
      if (lo == 0) SC[(size_t)b * Cc + c] = sq * (1.f / (Kk * Rr));
    }
  }
}

// ---------------- fused: match scores + softmax + residual ----------------
__global__ __launch_bounds__(256) void softfin_kernel(const float* __restrict__ SWp,
                                                      const float* __restrict__ SC,
                                                      const float* __restrict__ span_t,
                                                      const float* __restrict__ PS,
                                                      const float* __restrict__ G,
                                                      const float* __restrict__ Au,
                                                      const float* __restrict__ mhat,
                                                      float* __restrict__ out) {
  int b = blockIdx.x, t = threadIdx.x;
  int lane = t & 63, wave = t >> 6;
  __shared__ float redM[4], redS[4], redA[4];
  __shared__ float sb[Cc];
  __shared__ float au2[8][32];
  float span_norm = fminf(fmaxf(span_t[b] * (1.f / 20.f), 0.f), 1.f);
  float psn = 1.f / (1.f + expf(-PS[t]));
  float m = 0.f;
#pragma unroll
  for (int kc = 0; kc < SKW; ++kc) m += SWp[(size_t)kc * (Bb * Cc) + b * Cc + t];
  m += SC[b * Cc + t] - 0.3f * fabsf(span_norm - psn);
  float mx = m;
#pragma unroll
  for (int off = 32; off; off >>= 1) mx = fmaxf(mx, __shfl_xor(mx, off, 64));
  if (lane == 0) redM[wave] = mx;
  __syncthreads();
  mx = fmaxf(fmaxf(redM[0], redM[1]), fmaxf(redM[2], redM[3]));
  float e = expf(m - mx);
  float s = e;
#pragma unroll
  for (int off = 32; off; off >>= 1) s += __shfl_xor(s, off, 64);
  if (lane == 0) redS[wave] = s;
  __syncthreads();
  s = redS[0] + redS[1] + redS[2] + redS[3];
  float beta_t = e / s;
  sb[t] = beta_t;
  __syncthreads();
  // recon partial: w_t = sum_c beta_c G[c,t] (coalesced row-major reads)
  float w = 0.f;
#pragma unroll 8
  for (int c = 0; c < Cc; ++c) w = fmaf(sb[c], G[c * Cc + t], w);
  float pr = beta_t * w;
  // cross partials
  int r = t & 31, g = t >> 5;
  float pp = 0.f;
#pragma unroll 8
  for (int cc = 0; cc < 32; ++cc) {
    int c = cc * 8 + g;
    pp = fmaf(sb[c], Au[((size_t)b * Cc + c) * Rr + r], pp);
  }
  au2[g][r] = pp;
  float x = pr;
#pragma unroll
  for (int off = 32; off; off >>= 1) x += __shfl_xor(x, off, 64);
  if (lane == 0) redA[wave] = x;
  __syncthreads();
  float recon = (redA[0] + redA[1] + redA[2] + redA[3]) * (1.f / 4096.f);
  float cr = 0.f;
  if (t < 32) {
    float a2 = au2[0][t] + au2[1][t] + au2[2][t] + au2[3][t]
             + au2[4][t] + au2[5][t] + au2[6][t] + au2[7][t];
    cr = a2 * a2;
  }
#pragma unroll
  for (int off = 16; off; off >>= 1) cr += __shfl_xor(cr, off, 64);
  if (t == 0) {
    cr *= (1.f / 4096.f);
    float res = mhat[b] * (1.f / 128.f) - 2.f * cr + recon;
    out[b] = fminf(fmaxf(res, 0.f), 10000.f);
  }
}

extern "C" void kernel_launch(void* const* d_in, const int* in_sizes, int n_in,
                              void* d_out, int out_size, void* d_ws, size_t ws_size,
                              hipStream_t stream) {
  const float* A      = (const float*)d_in[0];
  const float* span_t = (const float*)d_in[1];
  const float* W      = (const float*)d_in[2];
  const float* U      = (const float*)d_in[3];
  const float* PS     = (const float*)d_in[4];
  float* out = (float*)d_out;

  char* p = (char*)d_ws;
  float* mhat = (float*)p; p += (size_t)Bb * 4;
  float* SWp  = (float*)p; p += (size_t)SKW * Bb * Cc * 4;
  float* SC   = (float*)p; p += (size_t)Bb * Cc * 4;
  float* G    = (float*)p; p += (size_t)Cc * Cc * 4;
  u16*   S    = (u16*)p;   p += (size_t)Bb * Nn * 2;
  float* Au   = (float*)p; p += (size_t)Bb * Cc * Rr * 4;
  size_t fixed = (size_t)(p - (char*)d_ws);
  size_t UTsz = (size_t)Cc * Lflat * 2;                       // 67 MB
  bool planA = ws_size >= fixed + UTsz + (size_t)3 * 8 * 16384 * 4;

  topk_kernel<<<dim3(Bb), dim3(256), 0, stream>>>(A, S, mhat);
  scorew_mfma_kernel<<<dim3(4, 4, SKW), dim3(256), 0, stream>>>(A, W, SWp);

  if (planA) {
    u16* UT = (u16*)p; p += UTsz;
    size_t used = fixed + UTsz;
    int nchunks = 64;
    while (nchunks > 8 && used + (size_t)(3 * nchunks) * 16384 * 4 > ws_size) nchunks >>= 1;
    float* Gpart = (float*)p;
    u2t_kernel<<<dim3(Cc, 8), dim3(256), 0, stream>>>(U, UT);
    gram_bf16_kernel<<<dim3(3 * nchunks), dim3(256), 0, stream>>>(UT, Gpart, Lflat / nchunks);
    gram_reduce_kernel<<<dim3(48), dim3(256), 0, stream>>>(Gpart, G, nchunks);
    au_gemm_kernel<<<dim3(128, 2), dim3(256), 0, stream>>>(S, UT, Au, SC);
  } else {
    int nchunks = 64;
    while (nchunks > 8 && fixed + (size_t)(3 * nchunks) * 16384 * 4 > ws_size) nchunks >>= 1;
    float* Gpart = (float*)p;
    gram_mfma_kernel<<<dim3(3 * nchunks), dim3(256), 0, stream>>>(U, Gpart, Lflat / nchunks);
    gram_reduce_kernel<<<dim3(48), dim3(256), 0, stream>>>(Gpart, G, nchunks);
    au_mfma_kernel<<<dim3(Cc, 2), dim3(256), 0, stream>>>(U, S, Au, SC);
  }

  softfin_kernel<<<dim3(Bb), dim3(256), 0, stream>>>(SWp, SC, span_t, PS, G, Au, mhat, out);
}